// Round 1
// baseline (802.124 us; speedup 1.0000x reference)
//
#include <hip/hip_runtime.h>
#include <hip/hip_bf16.h>

typedef __hip_bfloat16 BF;
typedef __attribute__((ext_vector_type(8))) short short8;
typedef __attribute__((ext_vector_type(4))) float f32x4;

#define DEV __device__ __forceinline__

// ---------------------------------------------------------------- helpers
DEV void gll16(const BF* g, BF* l) {
  __builtin_amdgcn_global_load_lds(
      (const __attribute__((address_space(1))) void*)g,
      (__attribute__((address_space(3))) void*)l, 16, 0, 0);
}

DEV unsigned short bfbits(float f) {
  BF b = __float2bfloat16(f);
  return *reinterpret_cast<unsigned short*>(&b);
}

// ---------------------------------------------------------------- f32 -> bf16
__global__ void f32_to_bf16_k(const float* __restrict__ in, BF* __restrict__ out, int n4) {
  int i = blockIdx.x * blockDim.x + threadIdx.x;
  if (i >= n4) return;
  const float4 v = ((const float4*)in)[i];
  ((ushort4*)out)[i] = make_ushort4(bfbits(v.x), bfbits(v.y), bfbits(v.z), bfbits(v.w));
}

// ---------------------------------------------------------------- GEMM (B^T form)
// C[m][n] = sum_k A[m][k] * Bm[n][k].  A: MxK row-major bf16, Bm: NxK row-major bf16.
// 128x128 tile, BK=64, 4 waves each 64x64, mfma 16x16x32 bf16.  (m97 structure)
template <typename CT>
__global__ __launch_bounds__(256) void gemm_bt(const BF* __restrict__ A,
                                               const BF* __restrict__ Bm,
                                               CT* __restrict__ C,
                                               const int M, const int N, const int K) {
  __shared__ __align__(16) BF As[128 * 64];
  __shared__ __align__(16) BF Bs[128 * 64];
  const int ntl = N >> 7;
  const int mt = blockIdx.x / ntl;
  const int nt = blockIdx.x % ntl;
  const int m0 = mt << 7, n0 = nt << 7;
  const int tid = threadIdx.x, lane = tid & 63, w = tid >> 6;
  const int l15 = lane & 15, g = lane >> 4;
  const int wm = w >> 1, wn = w & 1;

  f32x4 acc[4][4];
#pragma unroll
  for (int m = 0; m < 4; ++m)
#pragma unroll
    for (int n = 0; n < 4; ++n) acc[m][n] = (f32x4){0.f, 0.f, 0.f, 0.f};

  const int srow = lane >> 3;        // 8 lanes per 128B row
  const int sch = (lane & 7) << 3;   // element offset within row (x8 bf16)
  const int nkt = K >> 6;

  for (int kt = 0; kt < nkt; ++kt) {
    const int k0 = kt << 6;
#pragma unroll
    for (int i = 0; i < 4; ++i) {
      const int li = w * 4 + i;            // 1KB chunk id (covers 8 rows)
      const int row = li * 8 + srow;
      gll16(A + (size_t)(m0 + row) * K + k0 + sch, As + li * 512);
      gll16(Bm + (size_t)(n0 + row) * K + k0 + sch, Bs + li * 512);
    }
    __syncthreads();
#pragma unroll
    for (int kk = 0; kk < 2; ++kk) {
      short8 af[4], bfv[4];
#pragma unroll
      for (int m = 0; m < 4; ++m)
        af[m] = *(const short8*)&As[(wm * 64 + m * 16 + l15) * 64 + kk * 32 + g * 8];
#pragma unroll
      for (int n = 0; n < 4; ++n)
        bfv[n] = *(const short8*)&Bs[(wn * 64 + n * 16 + l15) * 64 + kk * 32 + g * 8];
#pragma unroll
      for (int m = 0; m < 4; ++m)
#pragma unroll
        for (int n = 0; n < 4; ++n)
          acc[m][n] = __builtin_amdgcn_mfma_f32_16x16x32_bf16(af[m], bfv[n], acc[m][n], 0, 0, 0);
    }
    __syncthreads();
  }
#pragma unroll
  for (int m = 0; m < 4; ++m) {
    const int gr = m0 + wm * 64 + m * 16 + g * 4;
#pragma unroll
    for (int n = 0; n < 4; ++n) {
      const int gc = n0 + wn * 64 + n * 16 + l15;
#pragma unroll
      for (int r = 0; r < 4; ++r) {
        const float v = acc[m][n][r];
        if constexpr (sizeof(CT) == 2)
          C[(size_t)(gr + r) * N + gc] = __float2bfloat16(v);
        else
          C[(size_t)(gr + r) * N + gc] = v;
      }
    }
  }
}

// ---------------------------------------------------------------- RMSNorm + RoPE
// One wave per 256-dim head-row of C1.  slot<16: q head; slot>=16: kv head (k).
// C1 row layout: [q 0..4095 | k 4096..6143 | v 6144..8191]
__global__ __launch_bounds__(256) void rmsrope(const BF* __restrict__ C1,
                                               BF* __restrict__ Qo, BF* __restrict__ Ko,
                                               const float* __restrict__ cosl,
                                               const float* __restrict__ sinl,
                                               const float* __restrict__ qw,
                                               const float* __restrict__ kw) {
  const int gwid = (blockIdx.x * 256 + threadIdx.x) >> 6;
  const int lane = threadIdx.x & 63;
  const int slot = gwid % 24;
  const int bt = gwid / 24;            // b*2048 + t
  const int b = bt >> 11, t = bt & 2047;
  const BF* src;
  BF* dst;
  const float* wgt;
  if (slot < 16) {
    src = C1 + (size_t)bt * 8192 + slot * 256;
    dst = Qo + ((size_t)(b * 16 + slot) * 2048 + t) * 256;
    wgt = qw;
  } else {
    const int kv = slot - 16;
    src = C1 + (size_t)bt * 8192 + 4096 + kv * 256;
    dst = Ko + ((size_t)(b * 8 + kv) * 2048 + t) * 256;
    wgt = kw;
  }
  float x0 = __bfloat162float(src[lane]);
  float x1 = __bfloat162float(src[lane + 64]);
  float x2 = __bfloat162float(src[lane + 128]);
  float x3 = __bfloat162float(src[lane + 192]);
  float ss = x0 * x0 + x1 * x1 + x2 * x2 + x3 * x3;
#pragma unroll
  for (int mm = 32; mm >= 1; mm >>= 1) ss += __shfl_xor(ss, mm);
  const float nrm = rsqrtf(ss * (1.f / 256.f) + 1e-6f);
  x0 *= nrm * wgt[lane];
  x1 *= nrm * wgt[lane + 64];
  x2 *= nrm * wgt[lane + 128];
  x3 *= nrm * wgt[lane + 192];
  const float c0 = cosl[t * 128 + lane], s0 = sinl[t * 128 + lane];
  const float c1 = cosl[t * 128 + lane + 64], s1 = sinl[t * 128 + lane + 64];
  dst[lane]       = __float2bfloat16(x0 * c0 - x2 * s0);
  dst[lane + 64]  = __float2bfloat16(x1 * c1 - x3 * s1);
  dst[lane + 128] = __float2bfloat16(x2 * c0 + x0 * s0);
  dst[lane + 192] = __float2bfloat16(x3 * c1 + x1 * s1);
}

// ---------------------------------------------------------------- V transpose
// C1 v-part [b][t][kv*256+d] (bf16) -> Vt [b*KV+kv][d (256)][t (2048)]
__global__ void vtrans(const BF* __restrict__ C1, BF* __restrict__ Vt) {
  __shared__ BF tile[32][33];
  const int bz = blockIdx.z;  // b*8+kv
  const int tt = blockIdx.x;  // t tile (64)
  const int dt = blockIdx.y;  // d tile (8)
  const int x = threadIdx.x, y0 = threadIdx.y;
  const int b = bz >> 3, kv = bz & 7;
#pragma unroll
  for (int yy = y0; yy < 32; yy += 8) {
    const int t = tt * 32 + yy, d = dt * 32 + x;
    tile[yy][x] = C1[((size_t)(b * 2048 + t)) * 8192 + 6144 + kv * 256 + d];
  }
  __syncthreads();
#pragma unroll
  for (int yy = y0; yy < 32; yy += 8) {
    const int d = dt * 32 + yy, t = tt * 32 + x;
    Vt[((size_t)bz * 256 + d) * 2048 + t] = tile[x][yy];
  }
}

// ---------------------------------------------------------------- flash attention
// grid (qt=32, b*H=32).  4 waves x 16 q-rows, 64-key tiles, window 1024 causal.
// K LDS [64][256] XOR-swizzled; Vt LDS [256][64] XOR-swizzled; P per-wave [16][64] swizzled.
__global__ __launch_bounds__(256, 2) void attn_fwd(const BF* __restrict__ Q,
                                                   const BF* __restrict__ K,
                                                   const BF* __restrict__ Vt,
                                                   BF* __restrict__ O) {
  __shared__ __align__(16) BF Ks[64 * 256];
  __shared__ __align__(16) BF Vs[256 * 64];
  __shared__ __align__(16) BF Ps[4][1024];
  const int tid = threadIdx.x;
  const int lane = tid & 63;
  const int w = tid >> 6;
  const int l15 = lane & 15;
  const int g = lane >> 4;
  const int qt = blockIdx.x;
  const int bh = blockIdx.y;
  const int b = bh >> 4, h = bh & 15;
  const int kvh = h >> 1;
  const int q0 = qt << 6;
  const BF* Qb = Q + ((size_t)bh * 2048 + q0) * 256;
  const BF* Kb = K + (size_t)(b * 8 + kvh) * 2048 * 256;
  const BF* Vb = Vt + (size_t)(b * 8 + kvh) * 256 * 2048;

  short8 qf[8];
  {
    const BF* qr = Qb + (w * 16 + l15) * 256 + g * 8;
#pragma unroll
    for (int kk = 0; kk < 8; ++kk) qf[kk] = *(const short8*)(qr + kk * 32);
  }
  f32x4 oacc[16];
#pragma unroll
  for (int i = 0; i < 16; ++i) oacc[i] = (f32x4){0.f, 0.f, 0.f, 0.f};
  float m_r[4] = {-1e30f, -1e30f, -1e30f, -1e30f};
  float l_r[4] = {0.f, 0.f, 0.f, 0.f};

  const int kt_lo = (q0 > 1023) ? ((q0 - 1023) >> 6) : 0;
  for (int kt = kt_lo; kt <= qt; ++kt) {
    const int tk = kt << 6;
    // stage K tile [64][256] and V^T tile [256][64]; pre-swizzled global source
#pragma unroll
    for (int i = 0; i < 8; ++i) {
      const int li = w * 8 + i;
      {
        const int row = li * 2 + (lane >> 5);
        const int ch = lane & 31;
        gll16(Kb + (size_t)(tk + row) * 256 + ((ch ^ (row & 7)) << 3), Ks + li * 512);
      }
      {
        const int row = li * 8 + (lane >> 3);
        const int ch = lane & 7;
        gll16(Vb + (size_t)row * 2048 + tk + ((ch ^ (row & 7)) << 3), Vs + li * 512);
      }
    }
    __syncthreads();

    // S = Q K^T (16 rows x 64 keys per wave)
    f32x4 sa[4];
#pragma unroll
    for (int i2 = 0; i2 < 4; ++i2) sa[i2] = (f32x4){0.f, 0.f, 0.f, 0.f};
#pragma unroll
    for (int kk = 0; kk < 8; ++kk) {
      const int d = kk * 32 + g * 8;
#pragma unroll
      for (int blk = 0; blk < 4; ++blk) {
        const int row = blk * 16 + l15;
        const short8 kf = *(const short8*)&Ks[row * 256 + (d ^ ((row & 7) << 3))];
        sa[blk] = __builtin_amdgcn_mfma_f32_16x16x32_bf16(qf[kk], kf, sa[blk], 0, 0, 0);
      }
    }

    // masked online softmax (per row group; 16 lanes share a row)
    float al4[4];
#pragma unroll
    for (int r = 0; r < 4; ++r) {
      const int qi = q0 + w * 16 + g * 4 + r;
      float pv[4];
      float tmax = -1e30f;
#pragma unroll
      for (int blk = 0; blk < 4; ++blk) {
        const int ki = tk + blk * 16 + l15;
        float sv = sa[blk][r] * 0.0625f;
        const bool ok = (ki <= qi) && (qi - ki < 1024);
        sv = ok ? sv : -1e30f;
        pv[blk] = sv;
        tmax = fmaxf(tmax, sv);
      }
#pragma unroll
      for (int mm = 1; mm < 16; mm <<= 1) tmax = fmaxf(tmax, __shfl_xor(tmax, mm));
      const float mn = fmaxf(m_r[r], tmax);
      const float alpha = __expf(m_r[r] - mn);
      float tsum = 0.f;
#pragma unroll
      for (int blk = 0; blk < 4; ++blk) {
        const float p = __expf(pv[blk] - mn);
        pv[blk] = p;
        tsum += p;
      }
#pragma unroll
      for (int mm = 1; mm < 16; mm <<= 1) tsum += __shfl_xor(tsum, mm);
      l_r[r] = l_r[r] * alpha + tsum;
      m_r[r] = mn;
      al4[r] = alpha;
      const int prow = g * 4 + r;
#pragma unroll
      for (int blk = 0; blk < 4; ++blk) {
        const int col = blk * 16 + l15;
        Ps[w][prow * 64 + (col ^ ((prow & 7) << 3))] = __float2bfloat16(pv[blk]);
      }
    }
#pragma unroll
    for (int db = 0; db < 16; ++db)
#pragma unroll
      for (int r = 0; r < 4; ++r) oacc[db][r] *= al4[r];

    // O += P V
#pragma unroll
    for (int kk2 = 0; kk2 < 2; ++kk2) {
      const int k8 = kk2 * 32 + g * 8;
      const short8 pf = *(const short8*)&Ps[w][l15 * 64 + (k8 ^ ((l15 & 7) << 3))];
#pragma unroll
      for (int db = 0; db < 16; ++db) {
        const int vrow = db * 16 + l15;
        const short8 vf = *(const short8*)&Vs[vrow * 64 + (k8 ^ ((vrow & 7) << 3))];
        oacc[db] = __builtin_amdgcn_mfma_f32_16x16x32_bf16(pf, vf, oacc[db], 0, 0, 0);
      }
    }
    __syncthreads();
  }

#pragma unroll
  for (int r = 0; r < 4; ++r) l_r[r] = 1.f / l_r[r];
  const size_t orow0 = (size_t)(b * 2048 + q0 + w * 16 + g * 4);
#pragma unroll
  for (int r = 0; r < 4; ++r) {
    BF* op = O + (orow0 + r) * 4096 + h * 256 + l15;
#pragma unroll
    for (int db = 0; db < 16; ++db) op[db * 16] = __float2bfloat16(oacc[db][r] * l_r[r]);
  }
}

// ---------------------------------------------------------------- launcher
// ws layout (bytes):
//   [0          , 62914560 )  Wqkv bf16 (8192x3840)   -> later reused: Q (33554432) + K (16777216)
//   [62914560   , 94371840 )  Wo bf16 (3840x4096)
//   [94371840   , 125829120)  Xbf bf16 (4096x3840)    -> later reused: Vt (16777216)
//   [125829120  , 192937984)  C1 bf16 (4096x8192)     -> later reused: attn out (33554432)
extern "C" void kernel_launch(void* const* d_in, const int* in_sizes, int n_in,
                              void* d_out, int out_size, void* d_ws, size_t ws_size,
                              hipStream_t stream) {
  (void)in_sizes; (void)n_in; (void)out_size;
  const float* x    = (const float*)d_in[0];
  const float* cosl = (const float*)d_in[3];   // reference uses LOCAL tables for q and k
  const float* sinl = (const float*)d_in[4];
  const float* wq   = (const float*)d_in[6];
  const float* wk   = (const float*)d_in[7];
  const float* wv   = (const float*)d_in[8];
  const float* wo   = (const float*)d_in[9];
  const float* qw   = (const float*)d_in[10];
  const float* kw   = (const float*)d_in[11];
  float* out = (float*)d_out;
  char* ws = (char*)d_ws;
  if (ws_size < 192937984ull) return;  // need ~184 MiB scratch

  BF* Wqkv = (BF*)(ws + 0);
  BF* Wo   = (BF*)(ws + 62914560);
  BF* Xbf  = (BF*)(ws + 94371840);
  BF* C1   = (BF*)(ws + 125829120);
  BF* Qb   = (BF*)(ws + 0);            // alias (Wqkv dead after GEMM1)
  BF* Kb   = (BF*)(ws + 33554432);
  BF* Vt   = (BF*)(ws + 94371840);     // alias (Xbf dead after GEMM1)
  BF* AO   = (BF*)(ws + 125829120);    // alias (C1 dead after rmsrope+vtrans)

  auto cvt = [&](const float* src, BF* dst, int n) {
    const int n4 = n >> 2;
    f32_to_bf16_k<<<(n4 + 255) / 256, 256, 0, stream>>>(src, dst, n4);
  };
  cvt(x,  Xbf, 4096 * 3840);
  cvt(wq, Wqkv, 4096 * 3840);
  cvt(wk, Wqkv + 4096 * 3840, 2048 * 3840);
  cvt(wv, Wqkv + 6144 * 3840, 2048 * 3840);
  cvt(wo, Wo, 3840 * 4096);

  gemm_bt<BF><<<2048, 256, 0, stream>>>(Xbf, Wqkv, C1, 4096, 8192, 3840);
  rmsrope<<<24576, 256, 0, stream>>>(C1, Qb, Kb, cosl, sinl, qw, kw);
  vtrans<<<dim3(64, 8, 16), dim3(32, 8), 0, stream>>>(C1, Vt);
  attn_fwd<<<dim3(32, 32), 256, 0, stream>>>(Qb, Kb, Vt, AO);
  gemm_bt<float><<<960, 256, 0, stream>>>(AO, Wo, out, 4096, 3840, 4096);
}

// Round 2
// 705.125 us; speedup vs baseline: 1.1376x; 1.1376x over previous
//
#include <hip/hip_runtime.h>
#include <hip/hip_bf16.h>

typedef __hip_bfloat16 BF;
typedef __attribute__((ext_vector_type(8))) short short8;
typedef __attribute__((ext_vector_type(4))) float f32x4;

#define DEV __device__ __forceinline__

// ---------------------------------------------------------------- helpers
DEV void gll16(const BF* g, BF* l) {
  __builtin_amdgcn_global_load_lds(
      (const __attribute__((address_space(1))) void*)g,
      (__attribute__((address_space(3))) void*)l, 16, 0, 0);
}

DEV unsigned short bfbits(float f) {
  BF b = __float2bfloat16(f);
  return *reinterpret_cast<unsigned short*>(&b);
}

// ---------------------------------------------------------------- f32 -> bf16
__global__ void f32_to_bf16_k(const float* __restrict__ in, BF* __restrict__ out, int n4) {
  int i = blockIdx.x * blockDim.x + threadIdx.x;
  if (i >= n4) return;
  const float4 v = ((const float4*)in)[i];
  ((ushort4*)out)[i] = make_ushort4(bfbits(v.x), bfbits(v.y), bfbits(v.z), bfbits(v.w));
}

// ---------------------------------------------------------------- GEMM (B^T form)
// C[m][n] = sum_k A[m][k] * Bm[n][k].  A: MxK row-major bf16, Bm: NxK row-major bf16.
// 128x128 tile, BK=64, 4 waves each 64x64, mfma 16x16x32 bf16.  (m97 structure)
// LDS tiles XOR-swizzled: linear gll16 dest + inverse-swizzled global source +
// swizzled ds_read col (slot ^= row&7) -> 2-way max bank aliasing (free).
template <typename CT>
__global__ __launch_bounds__(256) void gemm_bt(const BF* __restrict__ A,
                                               const BF* __restrict__ Bm,
                                               CT* __restrict__ C,
                                               const int M, const int N, const int K) {
  __shared__ __align__(16) BF As[128 * 64];
  __shared__ __align__(16) BF Bs[128 * 64];
  const int ntl = N >> 7;
  // bijective XCD-aware swizzle (gridDim.x % 8 == 0 for all our launches)
  const int cpx = gridDim.x >> 3;
  const int swzb = (blockIdx.x & 7) * cpx + (blockIdx.x >> 3);
  const int mt = swzb / ntl;
  const int nt = swzb % ntl;
  const int m0 = mt << 7, n0 = nt << 7;
  const int tid = threadIdx.x, lane = tid & 63, w = tid >> 6;
  const int l15 = lane & 15, g = lane >> 4;
  const int r7 = l15 & 7;
  const int wm = w >> 1, wn = w & 1;

  f32x4 acc[4][4];
#pragma unroll
  for (int m = 0; m < 4; ++m)
#pragma unroll
    for (int n = 0; n < 4; ++n) acc[m][n] = (f32x4){0.f, 0.f, 0.f, 0.f};

  const int srow = lane >> 3;                          // 8 lanes per 128B row
  const int sch = ((lane & 7) ^ (lane >> 3)) << 3;     // inverse-swizzled source col
  const int nkt = K >> 6;

  for (int kt = 0; kt < nkt; ++kt) {
    const int k0 = kt << 6;
#pragma unroll
    for (int i = 0; i < 4; ++i) {
      const int li = w * 4 + i;            // 1KB chunk id (covers 8 rows)
      const int row = li * 8 + srow;
      gll16(A + (size_t)(m0 + row) * K + k0 + sch, As + li * 512);
      gll16(Bm + (size_t)(n0 + row) * K + k0 + sch, Bs + li * 512);
    }
    __syncthreads();
#pragma unroll
    for (int kk = 0; kk < 2; ++kk) {
      const int csl = (((kk << 2) | g) ^ r7) << 3;     // swizzled read col (elems)
      short8 af[4], bfv[4];
#pragma unroll
      for (int m = 0; m < 4; ++m)
        af[m] = *(const short8*)&As[(wm * 64 + m * 16 + l15) * 64 + csl];
#pragma unroll
      for (int n = 0; n < 4; ++n)
        bfv[n] = *(const short8*)&Bs[(wn * 64 + n * 16 + l15) * 64 + csl];
#pragma unroll
      for (int m = 0; m < 4; ++m)
#pragma unroll
        for (int n = 0; n < 4; ++n)
          acc[m][n] = __builtin_amdgcn_mfma_f32_16x16x32_bf16(af[m], bfv[n], acc[m][n], 0, 0, 0);
    }
    __syncthreads();
  }
#pragma unroll
  for (int m = 0; m < 4; ++m) {
    const int gr = m0 + wm * 64 + m * 16 + g * 4;
#pragma unroll
    for (int n = 0; n < 4; ++n) {
      const int gc = n0 + wn * 64 + n * 16 + l15;
#pragma unroll
      for (int r = 0; r < 4; ++r) {
        const float v = acc[m][n][r];
        if constexpr (sizeof(CT) == 2)
          C[(size_t)(gr + r) * N + gc] = __float2bfloat16(v);
        else
          C[(size_t)(gr + r) * N + gc] = v;
      }
    }
  }
}

// ---------------------------------------------------------------- RMSNorm + RoPE
// One wave per 256-dim head-row of C1.  slot<16: q head; slot>=16: kv head (k).
// C1 row layout: [q 0..4095 | k 4096..6143 | v 6144..8191]
__global__ __launch_bounds__(256) void rmsrope(const BF* __restrict__ C1,
                                               BF* __restrict__ Qo, BF* __restrict__ Ko,
                                               const float* __restrict__ cosl,
                                               const float* __restrict__ sinl,
                                               const float* __restrict__ qw,
                                               const float* __restrict__ kw) {
  const int gwid = (blockIdx.x * 256 + threadIdx.x) >> 6;
  const int lane = threadIdx.x & 63;
  const int slot = gwid % 24;
  const int bt = gwid / 24;            // b*2048 + t
  const int b = bt >> 11, t = bt & 2047;
  const BF* src;
  BF* dst;
  const float* wgt;
  if (slot < 16) {
    src = C1 + (size_t)bt * 8192 + slot * 256;
    dst = Qo + ((size_t)(b * 16 + slot) * 2048 + t) * 256;
    wgt = qw;
  } else {
    const int kv = slot - 16;
    src = C1 + (size_t)bt * 8192 + 4096 + kv * 256;
    dst = Ko + ((size_t)(b * 8 + kv) * 2048 + t) * 256;
    wgt = kw;
  }
  const int d2 = lane * 2;
  const ushort2 lo = *(const ushort2*)((const unsigned short*)src + d2);
  const ushort2 hi = *(const ushort2*)((const unsigned short*)src + 128 + d2);
  float x0 = __bfloat162float(*(const BF*)&lo.x);
  float x1 = __bfloat162float(*(const BF*)&lo.y);
  float x2 = __bfloat162float(*(const BF*)&hi.x);
  float x3 = __bfloat162float(*(const BF*)&hi.y);
  float ss = x0 * x0 + x1 * x1 + x2 * x2 + x3 * x3;
#pragma unroll
  for (int mm = 32; mm >= 1; mm >>= 1) ss += __shfl_xor(ss, mm);
  const float nrm = rsqrtf(ss * (1.f / 256.f) + 1e-6f);
  const float2 wlo = *(const float2*)(wgt + d2);
  const float2 whi = *(const float2*)(wgt + 128 + d2);
  x0 *= nrm * wlo.x;
  x1 *= nrm * wlo.y;
  x2 *= nrm * whi.x;
  x3 *= nrm * whi.y;
  const float2 c = *(const float2*)(cosl + t * 128 + d2);
  const float2 s = *(const float2*)(sinl + t * 128 + d2);
  ushort2 olo, ohi;
  olo.x = bfbits(x0 * c.x - x2 * s.x);
  olo.y = bfbits(x1 * c.y - x3 * s.y);
  ohi.x = bfbits(x2 * c.x + x0 * s.x);
  ohi.y = bfbits(x3 * c.y + x1 * s.y);
  *(ushort2*)((unsigned short*)dst + d2) = olo;
  *(ushort2*)((unsigned short*)dst + 128 + d2) = ohi;
}

// ---------------------------------------------------------------- V transpose
// C1 v-part [b][t][kv*256+d] (bf16) -> Vt [b*KV+kv][d (256)][t (2048)]
__global__ void vtrans(const BF* __restrict__ C1, BF* __restrict__ Vt) {
  __shared__ BF tile[32][33];
  const int bz = blockIdx.z;  // b*8+kv
  const int tt = blockIdx.x;  // t tile (64)
  const int dt = blockIdx.y;  // d tile (8)
  const int x = threadIdx.x, y0 = threadIdx.y;
  const int b = bz >> 3, kv = bz & 7;
#pragma unroll
  for (int yy = y0; yy < 32; yy += 8) {
    const int t = tt * 32 + yy, d = dt * 32 + x;
    tile[yy][x] = C1[((size_t)(b * 2048 + t)) * 8192 + 6144 + kv * 256 + d];
  }
  __syncthreads();
#pragma unroll
  for (int yy = y0; yy < 32; yy += 8) {
    const int d = dt * 32 + yy, t = tt * 32 + x;
    Vt[((size_t)bz * 256 + d) * 2048 + t] = tile[x][yy];
  }
}

// ---------------------------------------------------------------- flash attention
// grid (qt=32, b*H=32).  4 waves x 16 q-rows, 64-key tiles, window 1024 causal.
// K LDS [64][256] XOR-swizzled; Vt LDS [256][64] XOR-swizzled; P per-wave [16][64] swizzled.
__global__ __launch_bounds__(256, 2) void attn_fwd(const BF* __restrict__ Q,
                                                   const BF* __restrict__ K,
                                                   const BF* __restrict__ Vt,
                                                   BF* __restrict__ O) {
  __shared__ __align__(16) BF Ks[64 * 256];
  __shared__ __align__(16) BF Vs[256 * 64];
  __shared__ __align__(16) BF Ps[4][1024];
  const int tid = threadIdx.x;
  const int lane = tid & 63;
  const int w = tid >> 6;
  const int l15 = lane & 15;
  const int g = lane >> 4;
  const int qt = blockIdx.x;
  const int bh = blockIdx.y;
  const int b = bh >> 4, h = bh & 15;
  const int kvh = h >> 1;
  const int q0 = qt << 6;
  const BF* Qb = Q + ((size_t)bh * 2048 + q0) * 256;
  const BF* Kb = K + (size_t)(b * 8 + kvh) * 2048 * 256;
  const BF* Vb = Vt + (size_t)(b * 8 + kvh) * 256 * 2048;

  short8 qf[8];
  {
    const BF* qr = Qb + (w * 16 + l15) * 256 + g * 8;
#pragma unroll
    for (int kk = 0; kk < 8; ++kk) qf[kk] = *(const short8*)(qr + kk * 32);
  }
  f32x4 oacc[16];
#pragma unroll
  for (int i = 0; i < 16; ++i) oacc[i] = (f32x4){0.f, 0.f, 0.f, 0.f};
  float m_r[4] = {-1e30f, -1e30f, -1e30f, -1e30f};
  float l_r[4] = {0.f, 0.f, 0.f, 0.f};

  const int kt_lo = (q0 > 1023) ? ((q0 - 1023) >> 6) : 0;
  for (int kt = kt_lo; kt <= qt; ++kt) {
    const int tk = kt << 6;
    // stage K tile [64][256] and V^T tile [256][64]; pre-swizzled global source
#pragma unroll
    for (int i = 0; i < 8; ++i) {
      const int li = w * 8 + i;
      {
        const int row = li * 2 + (lane >> 5);
        const int ch = lane & 31;
        gll16(Kb + (size_t)(tk + row) * 256 + ((ch ^ (row & 7)) << 3), Ks + li * 512);
      }
      {
        const int row = li * 8 + (lane >> 3);
        const int ch = lane & 7;
        gll16(Vb + (size_t)row * 2048 + tk + ((ch ^ (row & 7)) << 3), Vs + li * 512);
      }
    }
    __syncthreads();

    // S = Q K^T (16 rows x 64 keys per wave)
    f32x4 sa[4];
#pragma unroll
    for (int i2 = 0; i2 < 4; ++i2) sa[i2] = (f32x4){0.f, 0.f, 0.f, 0.f};
#pragma unroll
    for (int kk = 0; kk < 8; ++kk) {
      const int d = kk * 32 + g * 8;
#pragma unroll
      for (int blk = 0; blk < 4; ++blk) {
        const int row = blk * 16 + l15;
        const short8 kf = *(const short8*)&Ks[row * 256 + (d ^ ((row & 7) << 3))];
        sa[blk] = __builtin_amdgcn_mfma_f32_16x16x32_bf16(qf[kk], kf, sa[blk], 0, 0, 0);
      }
    }

    // masked online softmax (per row group; 16 lanes share a row)
    float al4[4];
#pragma unroll
    for (int r = 0; r < 4; ++r) {
      const int qi = q0 + w * 16 + g * 4 + r;
      float pv[4];
      float tmax = -1e30f;
#pragma unroll
      for (int blk = 0; blk < 4; ++blk) {
        const int ki = tk + blk * 16 + l15;
        float sv = sa[blk][r] * 0.0625f;
        const bool ok = (ki <= qi) && (qi - ki < 1024);
        sv = ok ? sv : -1e30f;
        pv[blk] = sv;
        tmax = fmaxf(tmax, sv);
      }
#pragma unroll
      for (int mm = 1; mm < 16; mm <<= 1) tmax = fmaxf(tmax, __shfl_xor(tmax, mm));
      const float mn = fmaxf(m_r[r], tmax);
      const float alpha = __expf(m_r[r] - mn);
      float tsum = 0.f;
#pragma unroll
      for (int blk = 0; blk < 4; ++blk) {
        const float p = __expf(pv[blk] - mn);
        pv[blk] = p;
        tsum += p;
      }
#pragma unroll
      for (int mm = 1; mm < 16; mm <<= 1) tsum += __shfl_xor(tsum, mm);
      l_r[r] = l_r[r] * alpha + tsum;
      m_r[r] = mn;
      al4[r] = alpha;
      const int prow = g * 4 + r;
#pragma unroll
      for (int blk = 0; blk < 4; ++blk) {
        const int col = blk * 16 + l15;
        Ps[w][prow * 64 + (col ^ ((prow & 7) << 3))] = __float2bfloat16(pv[blk]);
      }
    }
#pragma unroll
    for (int db = 0; db < 16; ++db)
#pragma unroll
      for (int r = 0; r < 4; ++r) oacc[db][r] *= al4[r];

    // O += P V
#pragma unroll
    for (int kk2 = 0; kk2 < 2; ++kk2) {
      const int k8 = kk2 * 32 + g * 8;
      const short8 pf = *(const short8*)&Ps[w][l15 * 64 + (k8 ^ ((l15 & 7) << 3))];
#pragma unroll
      for (int db = 0; db < 16; ++db) {
        const int vrow = db * 16 + l15;
        const short8 vf = *(const short8*)&Vs[vrow * 64 + (k8 ^ ((vrow & 7) << 3))];
        oacc[db] = __builtin_amdgcn_mfma_f32_16x16x32_bf16(pf, vf, oacc[db], 0, 0, 0);
      }
    }
    __syncthreads();
  }

#pragma unroll
  for (int r = 0; r < 4; ++r) l_r[r] = 1.f / l_r[r];
  const size_t orow0 = (size_t)(b * 2048 + q0 + w * 16 + g * 4);
#pragma unroll
  for (int r = 0; r < 4; ++r) {
    BF* op = O + (orow0 + r) * 4096 + h * 256 + l15;
#pragma unroll
    for (int db = 0; db < 16; ++db) op[db * 16] = __float2bfloat16(oacc[db][r] * l_r[r]);
  }
}

// ---------------------------------------------------------------- launcher
// ws layout (bytes):
//   [0          , 62914560 )  Wqkv bf16 (8192x3840)   -> later reused: Q (33554432) + K (16777216)
//   [62914560   , 94371840 )  Wo bf16 (3840x4096)
//   [94371840   , 125829120)  Xbf bf16 (4096x3840)    -> later reused: Vt (16777216)
//   [125829120  , 192937984)  C1 bf16 (4096x8192)     -> later reused: attn out (33554432)
extern "C" void kernel_launch(void* const* d_in, const int* in_sizes, int n_in,
                              void* d_out, int out_size, void* d_ws, size_t ws_size,
                              hipStream_t stream) {
  (void)in_sizes; (void)n_in; (void)out_size;
  const float* x    = (const float*)d_in[0];
  const float* cosl = (const float*)d_in[3];   // reference uses LOCAL tables for q and k
  const float* sinl = (const float*)d_in[4];
  const float* wq   = (const float*)d_in[6];
  const float* wk   = (const float*)d_in[7];
  const float* wv   = (const float*)d_in[8];
  const float* wo   = (const float*)d_in[9];
  const float* qw   = (const float*)d_in[10];
  const float* kw   = (const float*)d_in[11];
  float* out = (float*)d_out;
  char* ws = (char*)d_ws;
  if (ws_size < 192937984ull) return;  // need ~184 MiB scratch

  BF* Wqkv = (BF*)(ws + 0);
  BF* Wo   = (BF*)(ws + 62914560);
  BF* Xbf  = (BF*)(ws + 94371840);
  BF* C1   = (BF*)(ws + 125829120);
  BF* Qb   = (BF*)(ws + 0);            // alias (Wqkv dead after GEMM1)
  BF* Kb   = (BF*)(ws + 33554432);
  BF* Vt   = (BF*)(ws + 94371840);     // alias (Xbf dead after GEMM1)
  BF* AO   = (BF*)(ws + 125829120);    // alias (C1 dead after rmsrope+vtrans)

  auto cvt = [&](const float* src, BF* dst, int n) {
    const int n4 = n >> 2;
    f32_to_bf16_k<<<(n4 + 255) / 256, 256, 0, stream>>>(src, dst, n4);
  };
  cvt(x,  Xbf, 4096 * 3840);
  cvt(wq, Wqkv, 4096 * 3840);
  cvt(wk, Wqkv + 4096 * 3840, 2048 * 3840);
  cvt(wv, Wqkv + 6144 * 3840, 2048 * 3840);
  cvt(wo, Wo, 3840 * 4096);

  gemm_bt<BF><<<2048, 256, 0, stream>>>(Xbf, Wqkv, C1, 4096, 8192, 3840);
  rmsrope<<<24576, 256, 0, stream>>>(C1, Qb, Kb, cosl, sinl, qw, kw);
  vtrans<<<dim3(64, 8, 16), dim3(32, 8), 0, stream>>>(C1, Vt);
  attn_fwd<<<dim3(32, 32), 256, 0, stream>>>(Qb, Kb, Vt, AO);
  gemm_bt<float><<<960, 256, 0, stream>>>(AO, Wo, out, 4096, 3840, 4096);
}

// Round 3
// 602.619 us; speedup vs baseline: 1.3311x; 1.1701x over previous
//
#include <hip/hip_runtime.h>
#include <hip/hip_bf16.h>

typedef __hip_bfloat16 BF;
typedef __attribute__((ext_vector_type(8))) short short8;
typedef __attribute__((ext_vector_type(4))) float f32x4;

#define DEV __device__ __forceinline__

// ---------------------------------------------------------------- helpers
DEV void gll16(const BF* g, BF* l) {
  __builtin_amdgcn_global_load_lds(
      (const __attribute__((address_space(1))) void*)g,
      (__attribute__((address_space(3))) void*)l, 16, 0, 0);
}

DEV void stage2(const BF* src, size_t rstp, BF* dst) {   // one 128x32 half-tile
  gll16(src, dst);
  gll16(src + rstp, dst + 4096);
}

DEV unsigned short bfbits(float f) {
  BF b = __float2bfloat16(f);
  return *reinterpret_cast<unsigned short*>(&b);
}

// ---------------------------------------------------------------- f32 -> bf16
__global__ void f32_to_bf16_k(const float* __restrict__ in, BF* __restrict__ out, int n4) {
  int i = blockIdx.x * blockDim.x + threadIdx.x;
  if (i >= n4) return;
  const float4 v = ((const float4*)in)[i];
  ((ushort4*)out)[i] = make_ushort4(bfbits(v.x), bfbits(v.y), bfbits(v.z), bfbits(v.w));
}

// ---------------------------------------------------------------- 256^2 8-phase GEMM (B^T)
// C[m][n] = sum_k A[m][k]*Bm[n][k].  BM=BN=256, BK=64, 8 waves (2M x 4N),
// per-wave 128x64 out.  LDS: per matrix 2 bufs x [kk(2)][256][32] bf16 = 128 KiB total.
// 8 phases / 2 K-tiles, counted vmcnt(4) at group boundaries (T3+T4), setprio (T5),
// 2-way-free XOR swizzle slot = g ^ ((row>>1)&3) staged via inverse-swizzled source (T2).
#define PHASE(MH, KK, STAGE, TAIL)                                                   \
  {                                                                                  \
    short8 af[4], bfr[4];                                                            \
    const BF* Ap = Ax + (KK)*8192;                                                   \
    const BF* Bp = Bx + (KK)*8192;                                                   \
    _Pragma("unroll") for (int m = 0; m < 4; ++m)                                    \
        af[m] = *(const short8*)&Ap[(wm*128 + (MH)*64 + m*16 + l15) * 32 + rd8];     \
    _Pragma("unroll") for (int n = 0; n < 4; ++n)                                    \
        bfr[n] = *(const short8*)&Bp[(wn*64 + n*16 + l15) * 32 + rd8];               \
    STAGE                                                                            \
    __builtin_amdgcn_s_barrier();                                                    \
    asm volatile("s_waitcnt lgkmcnt(0)" ::: "memory");                               \
    __builtin_amdgcn_sched_barrier(0);                                               \
    __builtin_amdgcn_s_setprio(1);                                                   \
    _Pragma("unroll") for (int m = 0; m < 4; ++m)                                    \
      _Pragma("unroll") for (int n = 0; n < 4; ++n)                                  \
        acc[(MH)*4 + m][n] =                                                         \
            __builtin_amdgcn_mfma_f32_16x16x32_bf16(af[m], bfr[n], acc[(MH)*4+m][n], 0, 0, 0); \
    __builtin_amdgcn_s_setprio(0);                                                   \
    TAIL                                                                             \
    __builtin_amdgcn_s_barrier();                                                    \
  }

template <typename CT>
__global__ __launch_bounds__(512, 2) void gemm256_bt(const BF* __restrict__ A,
                                                     const BF* __restrict__ Bm,
                                                     CT* __restrict__ C,
                                                     const int M, const int N, const int K) {
  extern __shared__ __align__(16) BF lds[];   // A: [0,32768) elems, B: [32768,65536)
  BF* ldsA = lds;
  BF* ldsB = lds + 32768;
  const int ntl = N >> 8;
  const int cpx = gridDim.x >> 3;              // bijective XCD swizzle (grid % 8 == 0)
  const int swzb = (blockIdx.x & 7) * cpx + (blockIdx.x >> 3);
  const int mt = swzb / ntl, nt = swzb % ntl;
  const int m0 = mt << 8, n0 = nt << 8;
  const int tid = threadIdx.x, lane = tid & 63, w = tid >> 6;
  const int l15 = lane & 15, g = lane >> 4;
  const int wm = w >> 2, wn = w & 3;
  const int rd8 = (g ^ ((l15 >> 1) & 3)) << 3;           // swizzled read slot (elems)
  const int trow = tid >> 2;                             // 0..127
  const int scol = ((lane & 3) ^ ((lane >> 3) & 3)) << 3; // inverse-swizzled src col
  const BF* aS = A + (size_t)(m0 + trow) * K + scol;
  const BF* bS = Bm + (size_t)(n0 + trow) * K + scol;
  const size_t rstp = (size_t)128 * K;
  BF* dA = ldsA + w * 512;                               // wave-uniform LDS dest base
  BF* dB = ldsB + w * 512;
  const int NT = K >> 6;

  f32x4 acc[8][4];
#pragma unroll
  for (int m = 0; m < 8; ++m)
#pragma unroll
    for (int n = 0; n < 4; ++n) acc[m][n] = (f32x4){0.f, 0.f, 0.f, 0.f};

  // prologue: tile0 (4 halves -> buf0), A_k0(1), B_k0(1) -> buf1
  stage2(aS, rstp, dA);
  stage2(bS, rstp, dB);
  stage2(aS + 32, rstp, dA + 8192);
  stage2(bS + 32, rstp, dB + 8192);
  stage2(aS + 64, rstp, dA + 16384);
  stage2(bS + 64, rstp, dB + 16384);
  asm volatile("s_waitcnt vmcnt(4)" ::: "memory");   // tile0 landed; tile1 k0-halves in flight
  __builtin_amdgcn_s_barrier();

  for (int t = 0; t < NT; ++t) {
    const int bX = (t & 1) << 14;                    // 0 or 16384
    const int bY = bX ^ 16384;
    const BF* Ax = ldsA + bX;
    const BF* Bx = ldsB + bX;
    const int kc1 = (t + 1) << 6, kc2 = (t + 2) << 6;
    const bool s1 = (t + 1 < NT), s2 = (t + 2 < NT);
    // p0 (mh0,kk0): stage A_k1(t+1) -> Y   [Y.kk1 dead since prev group p3]
    PHASE(0, 0, if (s1) stage2(aS + kc1 + 32, rstp, dA + bY + 8192);, )
    // p1 (mh1,kk0): stage B_k1(t+1) -> Y
    PHASE(1, 0, if (s1) stage2(bS + kc1 + 32, rstp, dB + bY + 8192);, )
    // p2 (mh0,kk1): stage A_k0(t+2) -> X   [X.kk0 dead after p1]
    PHASE(0, 1, if (s2) stage2(aS + kc2, rstp, dA + bX);, )
    // p3 (mh1,kk1): stage B_k0(t+2) -> X; boundary wait (counted, never 0 in steady state)
    PHASE(1, 1, if (s2) stage2(bS + kc2, rstp, dB + bX);,
          if (s2) { asm volatile("s_waitcnt vmcnt(4)" ::: "memory"); }
          else    { asm volatile("s_waitcnt vmcnt(0)" ::: "memory"); } )
  }

#pragma unroll
  for (int mi = 0; mi < 8; ++mi) {
    const int gr = m0 + wm * 128 + mi * 16 + g * 4;
#pragma unroll
    for (int n = 0; n < 4; ++n) {
      const int gc = n0 + wn * 64 + n * 16 + l15;
#pragma unroll
      for (int r = 0; r < 4; ++r) {
        const float v = acc[mi][n][r];
        if constexpr (sizeof(CT) == 2)
          C[(size_t)(gr + r) * N + gc] = __float2bfloat16(v);
        else
          C[(size_t)(gr + r) * N + gc] = v;
      }
    }
  }
}

// ---------------------------------------------------------------- RMSNorm + RoPE
__global__ __launch_bounds__(256) void rmsrope(const BF* __restrict__ C1,
                                               BF* __restrict__ Qo, BF* __restrict__ Ko,
                                               const float* __restrict__ cosl,
                                               const float* __restrict__ sinl,
                                               const float* __restrict__ qw,
                                               const float* __restrict__ kw) {
  const int gwid = (blockIdx.x * 256 + threadIdx.x) >> 6;
  const int lane = threadIdx.x & 63;
  const int slot = gwid % 24;
  const int bt = gwid / 24;            // b*2048 + t
  const int b = bt >> 11, t = bt & 2047;
  const BF* src;
  BF* dst;
  const float* wgt;
  if (slot < 16) {
    src = C1 + (size_t)bt * 8192 + slot * 256;
    dst = Qo + ((size_t)(b * 16 + slot) * 2048 + t) * 256;
    wgt = qw;
  } else {
    const int kv = slot - 16;
    src = C1 + (size_t)bt * 8192 + 4096 + kv * 256;
    dst = Ko + ((size_t)(b * 8 + kv) * 2048 + t) * 256;
    wgt = kw;
  }
  const int d2 = lane * 2;
  const ushort2 lo = *(const ushort2*)((const unsigned short*)src + d2);
  const ushort2 hi = *(const ushort2*)((const unsigned short*)src + 128 + d2);
  float x0 = __bfloat162float(*(const BF*)&lo.x);
  float x1 = __bfloat162float(*(const BF*)&lo.y);
  float x2 = __bfloat162float(*(const BF*)&hi.x);
  float x3 = __bfloat162float(*(const BF*)&hi.y);
  float ss = x0 * x0 + x1 * x1 + x2 * x2 + x3 * x3;
#pragma unroll
  for (int mm = 32; mm >= 1; mm >>= 1) ss += __shfl_xor(ss, mm);
  const float nrm = rsqrtf(ss * (1.f / 256.f) + 1e-6f);
  const float2 wlo = *(const float2*)(wgt + d2);
  const float2 whi = *(const float2*)(wgt + 128 + d2);
  x0 *= nrm * wlo.x;
  x1 *= nrm * wlo.y;
  x2 *= nrm * whi.x;
  x3 *= nrm * whi.y;
  const float2 c = *(const float2*)(cosl + t * 128 + d2);
  const float2 s = *(const float2*)(sinl + t * 128 + d2);
  ushort2 olo, ohi;
  olo.x = bfbits(x0 * c.x - x2 * s.x);
  olo.y = bfbits(x1 * c.y - x3 * s.y);
  ohi.x = bfbits(x2 * c.x + x0 * s.x);
  ohi.y = bfbits(x3 * c.y + x1 * s.y);
  *(ushort2*)((unsigned short*)dst + d2) = olo;
  *(ushort2*)((unsigned short*)dst + 128 + d2) = ohi;
}

// ---------------------------------------------------------------- V transpose
__global__ void vtrans(const BF* __restrict__ C1, BF* __restrict__ Vt) {
  __shared__ BF tile[32][33];
  const int bz = blockIdx.z;  // b*8+kv
  const int tt = blockIdx.x;  // t tile
  const int dt = blockIdx.y;  // d tile
  const int x = threadIdx.x, y0 = threadIdx.y;
  const int b = bz >> 3, kv = bz & 7;
#pragma unroll
  for (int yy = y0; yy < 32; yy += 8) {
    const int t = tt * 32 + yy, d = dt * 32 + x;
    tile[yy][x] = C1[((size_t)(b * 2048 + t)) * 8192 + 6144 + kv * 256 + d];
  }
  __syncthreads();
#pragma unroll
  for (int yy = y0; yy < 32; yy += 8) {
    const int d = dt * 32 + yy, t = tt * 32 + x;
    Vt[((size_t)bz * 256 + d) * 2048 + t] = tile[x][yy];
  }
}

// ---------------------------------------------------------------- flash attention
__global__ __launch_bounds__(256, 2) void attn_fwd(const BF* __restrict__ Q,
                                                   const BF* __restrict__ K,
                                                   const BF* __restrict__ Vt,
                                                   BF* __restrict__ O) {
  __shared__ __align__(16) BF Ks[64 * 256];
  __shared__ __align__(16) BF Vs[256 * 64];
  __shared__ __align__(16) BF Ps[4][1024];
  const int tid = threadIdx.x;
  const int lane = tid & 63;
  const int w = tid >> 6;
  const int l15 = lane & 15;
  const int g = lane >> 4;
  const int qt = blockIdx.x;
  const int bh = blockIdx.y;
  const int b = bh >> 4, h = bh & 15;
  const int kvh = h >> 1;
  const int q0 = qt << 6;
  const BF* Qb = Q + ((size_t)bh * 2048 + q0) * 256;
  const BF* Kb = K + (size_t)(b * 8 + kvh) * 2048 * 256;
  const BF* Vb = Vt + (size_t)(b * 8 + kvh) * 256 * 2048;

  short8 qf[8];
  {
    const BF* qr = Qb + (w * 16 + l15) * 256 + g * 8;
#pragma unroll
    for (int kk = 0; kk < 8; ++kk) qf[kk] = *(const short8*)(qr + kk * 32);
  }
  f32x4 oacc[16];
#pragma unroll
  for (int i = 0; i < 16; ++i) oacc[i] = (f32x4){0.f, 0.f, 0.f, 0.f};
  float m_r[4] = {-1e30f, -1e30f, -1e30f, -1e30f};
  float l_r[4] = {0.f, 0.f, 0.f, 0.f};

  const int kt_lo = (q0 > 1023) ? ((q0 - 1023) >> 6) : 0;
  for (int kt = kt_lo; kt <= qt; ++kt) {
    const int tk = kt << 6;
#pragma unroll
    for (int i = 0; i < 8; ++i) {
      const int li = w * 8 + i;
      {
        const int row = li * 2 + (lane >> 5);
        const int ch = lane & 31;
        gll16(Kb + (size_t)(tk + row) * 256 + ((ch ^ (row & 7)) << 3), Ks + li * 512);
      }
      {
        const int row = li * 8 + (lane >> 3);
        const int ch = lane & 7;
        gll16(Vb + (size_t)row * 2048 + tk + ((ch ^ (row & 7)) << 3), Vs + li * 512);
      }
    }
    __syncthreads();

    f32x4 sa[4];
#pragma unroll
    for (int i2 = 0; i2 < 4; ++i2) sa[i2] = (f32x4){0.f, 0.f, 0.f, 0.f};
#pragma unroll
    for (int kk = 0; kk < 8; ++kk) {
      const int d = kk * 32 + g * 8;
#pragma unroll
      for (int blk = 0; blk < 4; ++blk) {
        const int row = blk * 16 + l15;
        const short8 kf = *(const short8*)&Ks[row * 256 + (d ^ ((row & 7) << 3))];
        sa[blk] = __builtin_amdgcn_mfma_f32_16x16x32_bf16(qf[kk], kf, sa[blk], 0, 0, 0);
      }
    }

    float al4[4];
#pragma unroll
    for (int r = 0; r < 4; ++r) {
      const int qi = q0 + w * 16 + g * 4 + r;
      float pv[4];
      float tmax = -1e30f;
#pragma unroll
      for (int blk = 0; blk < 4; ++blk) {
        const int ki = tk + blk * 16 + l15;
        float sv = sa[blk][r] * 0.0625f;
        const bool ok = (ki <= qi) && (qi - ki < 1024);
        sv = ok ? sv : -1e30f;
        pv[blk] = sv;
        tmax = fmaxf(tmax, sv);
      }
#pragma unroll
      for (int mm = 1; mm < 16; mm <<= 1) tmax = fmaxf(tmax, __shfl_xor(tmax, mm));
      const float mn = fmaxf(m_r[r], tmax);
      const float alpha = __expf(m_r[r] - mn);
      float tsum = 0.f;
#pragma unroll
      for (int blk = 0; blk < 4; ++blk) {
        const float p = __expf(pv[blk] - mn);
        pv[blk] = p;
        tsum += p;
      }
#pragma unroll
      for (int mm = 1; mm < 16; mm <<= 1) tsum += __shfl_xor(tsum, mm);
      l_r[r] = l_r[r] * alpha + tsum;
      m_r[r] = mn;
      al4[r] = alpha;
      const int prow = g * 4 + r;
#pragma unroll
      for (int blk = 0; blk < 4; ++blk) {
        const int col = blk * 16 + l15;
        Ps[w][prow * 64 + (col ^ ((prow & 7) << 3))] = __float2bfloat16(pv[blk]);
      }
    }
#pragma unroll
    for (int db = 0; db < 16; ++db)
#pragma unroll
      for (int r = 0; r < 4; ++r) oacc[db][r] *= al4[r];

#pragma unroll
    for (int kk2 = 0; kk2 < 2; ++kk2) {
      const int k8 = kk2 * 32 + g * 8;
      const short8 pf = *(const short8*)&Ps[w][l15 * 64 + (k8 ^ ((l15 & 7) << 3))];
#pragma unroll
      for (int db = 0; db < 16; ++db) {
        const int vrow = db * 16 + l15;
        const short8 vf = *(const short8*)&Vs[vrow * 64 + (k8 ^ ((vrow & 7) << 3))];
        oacc[db] = __builtin_amdgcn_mfma_f32_16x16x32_bf16(pf, vf, oacc[db], 0, 0, 0);
      }
    }
    __syncthreads();
  }

#pragma unroll
  for (int r = 0; r < 4; ++r) l_r[r] = 1.f / l_r[r];
  const size_t orow0 = (size_t)(b * 2048 + q0 + w * 16 + g * 4);
#pragma unroll
  for (int r = 0; r < 4; ++r) {
    BF* op = O + (orow0 + r) * 4096 + h * 256 + l15;
#pragma unroll
    for (int db = 0; db < 16; ++db) op[db * 16] = __float2bfloat16(oacc[db][r] * l_r[r]);
  }
}

// ---------------------------------------------------------------- launcher
extern "C" void kernel_launch(void* const* d_in, const int* in_sizes, int n_in,
                              void* d_out, int out_size, void* d_ws, size_t ws_size,
                              hipStream_t stream) {
  (void)in_sizes; (void)n_in; (void)out_size;
  const float* x    = (const float*)d_in[0];
  const float* cosl = (const float*)d_in[3];   // reference uses LOCAL tables for q and k
  const float* sinl = (const float*)d_in[4];
  const float* wq   = (const float*)d_in[6];
  const float* wk   = (const float*)d_in[7];
  const float* wv   = (const float*)d_in[8];
  const float* wo   = (const float*)d_in[9];
  const float* qw   = (const float*)d_in[10];
  const float* kw   = (const float*)d_in[11];
  float* out = (float*)d_out;
  char* ws = (char*)d_ws;
  if (ws_size < 192937984ull) return;

  BF* Wqkv = (BF*)(ws + 0);
  BF* Wo   = (BF*)(ws + 62914560);
  BF* Xbf  = (BF*)(ws + 94371840);
  BF* C1   = (BF*)(ws + 125829120);
  BF* Qb   = (BF*)(ws + 0);            // alias (Wqkv dead after GEMM1)
  BF* Kb   = (BF*)(ws + 33554432);
  BF* Vt   = (BF*)(ws + 94371840);     // alias (Xbf dead after GEMM1)
  BF* AO   = (BF*)(ws + 125829120);    // alias (C1 dead after rmsrope+vtrans)

  // allow 128 KiB dynamic LDS for the 8-phase GEMM
  hipFuncSetAttribute(reinterpret_cast<const void*>(gemm256_bt<BF>),
                      hipFuncAttributeMaxDynamicSharedMemorySize, 131072);
  hipFuncSetAttribute(reinterpret_cast<const void*>(gemm256_bt<float>),
                      hipFuncAttributeMaxDynamicSharedMemorySize, 131072);

  auto cvt = [&](const float* src, BF* dst, int n) {
    const int n4 = n >> 2;
    f32_to_bf16_k<<<(n4 + 255) / 256, 256, 0, stream>>>(src, dst, n4);
  };
  cvt(x,  Xbf, 4096 * 3840);
  cvt(wq, Wqkv, 4096 * 3840);
  cvt(wk, Wqkv + 4096 * 3840, 2048 * 3840);
  cvt(wv, Wqkv + 6144 * 3840, 2048 * 3840);
  cvt(wo, Wo, 3840 * 4096);

  gemm256_bt<BF><<<512, 512, 131072, stream>>>(Xbf, Wqkv, C1, 4096, 8192, 3840);
  rmsrope<<<24576, 256, 0, stream>>>(C1, Qb, Kb, cosl, sinl, qw, kw);
  vtrans<<<dim3(64, 8, 16), dim3(32, 8), 0, stream>>>(C1, Vt);
  attn_fwd<<<dim3(32, 32), 256, 0, stream>>>(Qb, Kb, Vt, AO);
  gemm256_bt<float><<<240, 512, 131072, stream>>>(AO, Wo, out, 4096, 3840, 4096);
}

// Round 4
// 601.040 us; speedup vs baseline: 1.3346x; 1.0026x over previous
//
#include <hip/hip_runtime.h>
#include <hip/hip_bf16.h>

typedef __hip_bfloat16 BF;
typedef __attribute__((ext_vector_type(8))) short short8;
typedef __attribute__((ext_vector_type(4))) float f32x4;

#define DEV __device__ __forceinline__

// ---------------------------------------------------------------- helpers
DEV void gll16(const BF* g, BF* l) {
  __builtin_amdgcn_global_load_lds(
      (const __attribute__((address_space(1))) void*)g,
      (__attribute__((address_space(3))) void*)l, 16, 0, 0);
}

DEV void stage2(const BF* src, size_t rstp, BF* dst) {   // one 128x32 half-tile
  gll16(src, dst);
  gll16(src + rstp, dst + 4096);
}

DEV unsigned short bfbits(float f) {
  BF b = __float2bfloat16(f);
  return *reinterpret_cast<unsigned short*>(&b);
}

// ---------------------------------------------------------------- f32 -> bf16
__global__ void f32_to_bf16_k(const float* __restrict__ in, BF* __restrict__ out, int n4) {
  int i = blockIdx.x * blockDim.x + threadIdx.x;
  if (i >= n4) return;
  const float4 v = ((const float4*)in)[i];
  ((ushort4*)out)[i] = make_ushort4(bfbits(v.x), bfbits(v.y), bfbits(v.z), bfbits(v.w));
}

// ---------------------------------------------------------------- 256^2 8-phase GEMM (B^T)
// C[m][n] = sum_k A[m][k]*Bm[n][k].  BM=BN=256, BK=64, 8 waves (2M x 4N),
// per-wave 128x64 out.  LDS: per matrix 2 bufs x [kk(2)][256][32] bf16 = 128 KiB total.
// Deep pipeline: 12 loads in flight; W2=vmcnt(8) end of p1 (protects kk1(t), issued
// 6 phases earlier at t-1 p0/p1); W1=vmcnt(8) at boundary (protects kk0(t+1), issued
// at t-1 p2/p3).  Counted, never 0 in steady state (T3+T4); setprio (T5); 2-way-free
// XOR swizzle staged via inverse-swizzled source (T2, both-sides rule).
#define PHASE(MH, KK, STAGE, TAIL)                                                   \
  {                                                                                  \
    short8 af[4], bfr[4];                                                            \
    const BF* Ap = Ax + (KK)*8192;                                                   \
    const BF* Bp = Bx + (KK)*8192;                                                   \
    _Pragma("unroll") for (int m = 0; m < 4; ++m)                                    \
        af[m] = *(const short8*)&Ap[(wm*128 + (MH)*64 + m*16 + l15) * 32 + rd8];     \
    _Pragma("unroll") for (int n = 0; n < 4; ++n)                                    \
        bfr[n] = *(const short8*)&Bp[(wn*64 + n*16 + l15) * 32 + rd8];               \
    STAGE                                                                            \
    __builtin_amdgcn_s_barrier();                                                    \
    asm volatile("s_waitcnt lgkmcnt(0)" ::: "memory");                               \
    __builtin_amdgcn_sched_barrier(0);                                               \
    __builtin_amdgcn_s_setprio(1);                                                   \
    _Pragma("unroll") for (int m = 0; m < 4; ++m)                                    \
      _Pragma("unroll") for (int n = 0; n < 4; ++n)                                  \
        acc[(MH)*4 + m][n] =                                                         \
            __builtin_amdgcn_mfma_f32_16x16x32_bf16(af[m], bfr[n], acc[(MH)*4+m][n], 0, 0, 0); \
    __builtin_amdgcn_s_setprio(0);                                                   \
    TAIL                                                                             \
    __builtin_amdgcn_s_barrier();                                                    \
  }

template <typename CT>
__global__ __launch_bounds__(512, 2) void gemm256_bt(const BF* __restrict__ A,
                                                     const BF* __restrict__ Bm,
                                                     CT* __restrict__ C,
                                                     const int M, const int N, const int K) {
  extern __shared__ __align__(16) BF lds[];   // A: [0,32768) elems, B: [32768,65536)
  BF* ldsA = lds;
  BF* ldsB = lds + 32768;
  const int ntl = N >> 8;
  const int cpx = gridDim.x >> 3;              // bijective XCD swizzle (grid % 8 == 0)
  const int swzb = (blockIdx.x & 7) * cpx + (blockIdx.x >> 3);
  const int mt = swzb / ntl, nt = swzb % ntl;
  const int m0 = mt << 8, n0 = nt << 8;
  const int tid = threadIdx.x, lane = tid & 63, w = tid >> 6;
  const int l15 = lane & 15, g = lane >> 4;
  const int wm = w >> 2, wn = w & 3;
  const int rd8 = (g ^ ((l15 >> 1) & 3)) << 3;           // swizzled read slot (elems)
  const int trow = tid >> 2;                             // 0..127
  const int scol = ((lane & 3) ^ ((lane >> 3) & 3)) << 3; // inverse-swizzled src col
  const BF* aS = A + (size_t)(m0 + trow) * K + scol;
  const BF* bS = Bm + (size_t)(n0 + trow) * K + scol;
  const size_t rstp = (size_t)128 * K;
  BF* dA = ldsA + w * 512;                               // wave-uniform LDS dest base
  BF* dB = ldsB + w * 512;
  const int NT = K >> 6;

  f32x4 acc[8][4];
#pragma unroll
  for (int m = 0; m < 8; ++m)
#pragma unroll
    for (int n = 0; n < 4; ++n) acc[m][n] = (f32x4){0.f, 0.f, 0.f, 0.f};

  // prologue: tile0 (4 halves -> buf0), A_k0(1), B_k0(1) -> buf1  (12 loads in flight)
  stage2(aS, rstp, dA);
  stage2(bS, rstp, dB);
  stage2(aS + 32, rstp, dA + 8192);
  stage2(bS + 32, rstp, dB + 8192);
  stage2(aS + 64, rstp, dA + 16384);
  stage2(bS + 64, rstp, dB + 16384);
  asm volatile("s_waitcnt vmcnt(8)" ::: "memory");   // tile0.kk0 landed
  __builtin_amdgcn_sched_barrier(0);
  __builtin_amdgcn_s_barrier();

  for (int t = 0; t < NT; ++t) {
    const int bX = (t & 1) << 14;                    // 0 or 16384
    const int bY = bX ^ 16384;
    const BF* Ax = ldsA + bX;
    const BF* Bx = ldsB + bX;
    const int kc1 = (t + 1) << 6, kc2 = (t + 2) << 6;
    const bool s1 = (t + 1 < NT), s2 = (t + 2 < NT);
    // p0 (mh0,kk0): stage A_k1(t+1) -> Y.kk1   [dead since t-1 p3]
    PHASE(0, 0, if (s1) stage2(aS + kc1 + 32, rstp, dA + bY + 8192);, )
    // p1 (mh1,kk0): stage B_k1(t+1) -> Y.kk1;  W2: kk1(t) landed (issued t-1 p0/p1)
    PHASE(1, 0, if (s1) stage2(bS + kc1 + 32, rstp, dB + bY + 8192);,
          { asm volatile("s_waitcnt vmcnt(8)" ::: "memory");
            __builtin_amdgcn_sched_barrier(0); } )
    // p2 (mh0,kk1): stage A_k0(t+2) -> X.kk0   [dead after p1]
    PHASE(0, 1, if (s2) stage2(aS + kc2, rstp, dA + bX);, )
    // p3 (mh1,kk1): stage B_k0(t+2) -> X.kk0;  W1: kk0(t+1) landed (issued t-1 p2/p3)
    PHASE(1, 1, if (s2) stage2(bS + kc2, rstp, dB + bX);,
          if (s2) { asm volatile("s_waitcnt vmcnt(8)" ::: "memory");
                    __builtin_amdgcn_sched_barrier(0); }
          else    { asm volatile("s_waitcnt vmcnt(0)" ::: "memory");
                    __builtin_amdgcn_sched_barrier(0); } )
  }

#pragma unroll
  for (int mi = 0; mi < 8; ++mi) {
    const int gr = m0 + wm * 128 + mi * 16 + g * 4;
#pragma unroll
    for (int n = 0; n < 4; ++n) {
      const int gc = n0 + wn * 64 + n * 16 + l15;
#pragma unroll
      for (int r = 0; r < 4; ++r) {
        const float v = acc[mi][n][r];
        if constexpr (sizeof(CT) == 2)
          C[(size_t)(gr + r) * N + gc] = __float2bfloat16(v);
        else
          C[(size_t)(gr + r) * N + gc] = v;
      }
    }
  }
}

// ---------------------------------------------------------------- RMSNorm + RoPE
__global__ __launch_bounds__(256) void rmsrope(const BF* __restrict__ C1,
                                               BF* __restrict__ Qo, BF* __restrict__ Ko,
                                               const float* __restrict__ cosl,
                                               const float* __restrict__ sinl,
                                               const float* __restrict__ qw,
                                               const float* __restrict__ kw) {
  const int gwid = (blockIdx.x * 256 + threadIdx.x) >> 6;
  const int lane = threadIdx.x & 63;
  const int slot = gwid % 24;
  const int bt = gwid / 24;            // b*2048 + t
  const int b = bt >> 11, t = bt & 2047;
  const BF* src;
  BF* dst;
  const float* wgt;
  if (slot < 16) {
    src = C1 + (size_t)bt * 8192 + slot * 256;
    dst = Qo + ((size_t)(b * 16 + slot) * 2048 + t) * 256;
    wgt = qw;
  } else {
    const int kv = slot - 16;
    src = C1 + (size_t)bt * 8192 + 4096 + kv * 256;
    dst = Ko + ((size_t)(b * 8 + kv) * 2048 + t) * 256;
    wgt = kw;
  }
  const int d2 = lane * 2;
  const ushort2 lo = *(const ushort2*)((const unsigned short*)src + d2);
  const ushort2 hi = *(const ushort2*)((const unsigned short*)src + 128 + d2);
  float x0 = __bfloat162float(*(const BF*)&lo.x);
  float x1 = __bfloat162float(*(const BF*)&lo.y);
  float x2 = __bfloat162float(*(const BF*)&hi.x);
  float x3 = __bfloat162float(*(const BF*)&hi.y);
  float ss = x0 * x0 + x1 * x1 + x2 * x2 + x3 * x3;
#pragma unroll
  for (int mm = 32; mm >= 1; mm >>= 1) ss += __shfl_xor(ss, mm);
  const float nrm = rsqrtf(ss * (1.f / 256.f) + 1e-6f);
  const float2 wlo = *(const float2*)(wgt + d2);
  const float2 whi = *(const float2*)(wgt + 128 + d2);
  x0 *= nrm * wlo.x;
  x1 *= nrm * wlo.y;
  x2 *= nrm * whi.x;
  x3 *= nrm * whi.y;
  const float2 c = *(const float2*)(cosl + t * 128 + d2);
  const float2 s = *(const float2*)(sinl + t * 128 + d2);
  ushort2 olo, ohi;
  olo.x = bfbits(x0 * c.x - x2 * s.x);
  olo.y = bfbits(x1 * c.y - x3 * s.y);
  ohi.x = bfbits(x2 * c.x + x0 * s.x);
  ohi.y = bfbits(x3 * c.y + x1 * s.y);
  *(ushort2*)((unsigned short*)dst + d2) = olo;
  *(ushort2*)((unsigned short*)dst + 128 + d2) = ohi;
}

// ---------------------------------------------------------------- V transpose
__global__ void vtrans(const BF* __restrict__ C1, BF* __restrict__ Vt) {
  __shared__ BF tile[32][33];
  const int bz = blockIdx.z;  // b*8+kv
  const int tt = blockIdx.x;  // t tile
  const int dt = blockIdx.y;  // d tile
  const int x = threadIdx.x, y0 = threadIdx.y;
  const int b = bz >> 3, kv = bz & 7;
#pragma unroll
  for (int yy = y0; yy < 32; yy += 8) {
    const int t = tt * 32 + yy, d = dt * 32 + x;
    tile[yy][x] = C1[((size_t)(b * 2048 + t)) * 8192 + 6144 + kv * 256 + d];
  }
  __syncthreads();
#pragma unroll
  for (int yy = y0; yy < 32; yy += 8) {
    const int d = dt * 32 + yy, t = tt * 32 + x;
    Vt[((size_t)bz * 256 + d) * 2048 + t] = tile[x][yy];
  }
}

// ---------------------------------------------------------------- flash attention
__global__ __launch_bounds__(256, 2) void attn_fwd(const BF* __restrict__ Q,
                                                   const BF* __restrict__ K,
                                                   const BF* __restrict__ Vt,
                                                   BF* __restrict__ O) {
  __shared__ __align__(16) BF Ks[64 * 256];
  __shared__ __align__(16) BF Vs[256 * 64];
  __shared__ __align__(16) BF Ps[4][1024];
  const int tid = threadIdx.x;
  const int lane = tid & 63;
  const int w = tid >> 6;
  const int l15 = lane & 15;
  const int g = lane >> 4;
  const int qt = blockIdx.x;
  const int bh = blockIdx.y;
  const int b = bh >> 4, h = bh & 15;
  const int kvh = h >> 1;
  const int q0 = qt << 6;
  const BF* Qb = Q + ((size_t)bh * 2048 + q0) * 256;
  const BF* Kb = K + (size_t)(b * 8 + kvh) * 2048 * 256;
  const BF* Vb = Vt + (size_t)(b * 8 + kvh) * 256 * 2048;

  short8 qf[8];
  {
    const BF* qr = Qb + (w * 16 + l15) * 256 + g * 8;
#pragma unroll
    for (int kk = 0; kk < 8; ++kk) qf[kk] = *(const short8*)(qr + kk * 32);
  }
  f32x4 oacc[16];
#pragma unroll
  for (int i = 0; i < 16; ++i) oacc[i] = (f32x4){0.f, 0.f, 0.f, 0.f};
  float m_r[4] = {-1e30f, -1e30f, -1e30f, -1e30f};
  float l_r[4] = {0.f, 0.f, 0.f, 0.f};

  const int kt_lo = (q0 > 1023) ? ((q0 - 1023) >> 6) : 0;
  for (int kt = kt_lo; kt <= qt; ++kt) {
    const int tk = kt << 6;
#pragma unroll
    for (int i = 0; i < 8; ++i) {
      const int li = w * 8 + i;
      {
        const int row = li * 2 + (lane >> 5);
        const int ch = lane & 31;
        gll16(Kb + (size_t)(tk + row) * 256 + ((ch ^ (row & 7)) << 3), Ks + li * 512);
      }
      {
        const int row = li * 8 + (lane >> 3);
        const int ch = lane & 7;
        gll16(Vb + (size_t)row * 2048 + tk + ((ch ^ (row & 7)) << 3), Vs + li * 512);
      }
    }
    __syncthreads();

    f32x4 sa[4];
#pragma unroll
    for (int i2 = 0; i2 < 4; ++i2) sa[i2] = (f32x4){0.f, 0.f, 0.f, 0.f};
#pragma unroll
    for (int kk = 0; kk < 8; ++kk) {
      const int d = kk * 32 + g * 8;
#pragma unroll
      for (int blk = 0; blk < 4; ++blk) {
        const int row = blk * 16 + l15;
        const short8 kf = *(const short8*)&Ks[row * 256 + (d ^ ((row & 7) << 3))];
        sa[blk] = __builtin_amdgcn_mfma_f32_16x16x32_bf16(qf[kk], kf, sa[blk], 0, 0, 0);
      }
    }

    float al4[4];
#pragma unroll
    for (int r = 0; r < 4; ++r) {
      const int qi = q0 + w * 16 + g * 4 + r;
      float pv[4];
      float tmax = -1e30f;
#pragma unroll
      for (int blk = 0; blk < 4; ++blk) {
        const int ki = tk + blk * 16 + l15;
        float sv = sa[blk][r] * 0.0625f;
        const bool ok = (ki <= qi) && (qi - ki < 1024);
        sv = ok ? sv : -1e30f;
        pv[blk] = sv;
        tmax = fmaxf(tmax, sv);
      }
#pragma unroll
      for (int mm = 1; mm < 16; mm <<= 1) tmax = fmaxf(tmax, __shfl_xor(tmax, mm));
      const float mn = fmaxf(m_r[r], tmax);
      const float alpha = __expf(m_r[r] - mn);
      float tsum = 0.f;
#pragma unroll
      for (int blk = 0; blk < 4; ++blk) {
        const float p = __expf(pv[blk] - mn);
        pv[blk] = p;
        tsum += p;
      }
#pragma unroll
      for (int mm = 1; mm < 16; mm <<= 1) tsum += __shfl_xor(tsum, mm);
      l_r[r] = l_r[r] * alpha + tsum;
      m_r[r] = mn;
      al4[r] = alpha;
      const int prow = g * 4 + r;
#pragma unroll
      for (int blk = 0; blk < 4; ++blk) {
        const int col = blk * 16 + l15;
        Ps[w][prow * 64 + (col ^ ((prow & 7) << 3))] = __float2bfloat16(pv[blk]);
      }
    }
#pragma unroll
    for (int db = 0; db < 16; ++db)
#pragma unroll
      for (int r = 0; r < 4; ++r) oacc[db][r] *= al4[r];

#pragma unroll
    for (int kk2 = 0; kk2 < 2; ++kk2) {
      const int k8 = kk2 * 32 + g * 8;
      const short8 pf = *(const short8*)&Ps[w][l15 * 64 + (k8 ^ ((l15 & 7) << 3))];
#pragma unroll
      for (int db = 0; db < 16; ++db) {
        const int vrow = db * 16 + l15;
        const short8 vf = *(const short8*)&Vs[vrow * 64 + (k8 ^ ((vrow & 7) << 3))];
        oacc[db] = __builtin_amdgcn_mfma_f32_16x16x32_bf16(pf, vf, oacc[db], 0, 0, 0);
      }
    }
    __syncthreads();
  }

#pragma unroll
  for (int r = 0; r < 4; ++r) l_r[r] = 1.f / l_r[r];
  const size_t orow0 = (size_t)(b * 2048 + q0 + w * 16 + g * 4);
#pragma unroll
  for (int r = 0; r < 4; ++r) {
    BF* op = O + (orow0 + r) * 4096 + h * 256 + l15;
#pragma unroll
    for (int db = 0; db < 16; ++db) op[db * 16] = __float2bfloat16(oacc[db][r] * l_r[r]);
  }
}

// ---------------------------------------------------------------- launcher
extern "C" void kernel_launch(void* const* d_in, const int* in_sizes, int n_in,
                              void* d_out, int out_size, void* d_ws, size_t ws_size,
                              hipStream_t stream) {
  (void)in_sizes; (void)n_in; (void)out_size;
  const float* x    = (const float*)d_in[0];
  const float* cosl = (const float*)d_in[3];   // reference uses LOCAL tables for q and k
  const float* sinl = (const float*)d_in[4];
  const float* wq   = (const float*)d_in[6];
  const float* wk   = (const float*)d_in[7];
  const float* wv   = (const float*)d_in[8];
  const float* wo   = (const float*)d_in[9];
  const float* qw   = (const float*)d_in[10];
  const float* kw   = (const float*)d_in[11];
  float* out = (float*)d_out;
  char* ws = (char*)d_ws;
  if (ws_size < 192937984ull) return;

  BF* Wqkv = (BF*)(ws + 0);
  BF* Wo   = (BF*)(ws + 62914560);
  BF* Xbf  = (BF*)(ws + 94371840);
  BF* C1   = (BF*)(ws + 125829120);
  BF* Qb   = (BF*)(ws + 0);            // alias (Wqkv dead after GEMM1)
  BF* Kb   = (BF*)(ws + 33554432);
  BF* Vt   = (BF*)(ws + 94371840);     // alias (Xbf dead after GEMM1)
  BF* AO   = (BF*)(ws + 125829120);    // alias (C1 dead after rmsrope+vtrans)

  // allow 128 KiB dynamic LDS for the 8-phase GEMM
  hipFuncSetAttribute(reinterpret_cast<const void*>(gemm256_bt<BF>),
                      hipFuncAttributeMaxDynamicSharedMemorySize, 131072);
  hipFuncSetAttribute(reinterpret_cast<const void*>(gemm256_bt<float>),
                      hipFuncAttributeMaxDynamicSharedMemorySize, 131072);

  auto cvt = [&](const float* src, BF* dst, int n) {
    const int n4 = n >> 2;
    f32_to_bf16_k<<<(n4 + 255) / 256, 256, 0, stream>>>(src, dst, n4);
  };
  cvt(x,  Xbf, 4096 * 3840);
  cvt(wq, Wqkv, 4096 * 3840);
  cvt(wk, Wqkv + 4096 * 3840, 2048 * 3840);
  cvt(wv, Wqkv + 6144 * 3840, 2048 * 3840);
  cvt(wo, Wo, 3840 * 4096);

  gemm256_bt<BF><<<512, 512, 131072, stream>>>(Xbf, Wqkv, C1, 4096, 8192, 3840);
  rmsrope<<<24576, 256, 0, stream>>>(C1, Qb, Kb, cosl, sinl, qw, kw);
  vtrans<<<dim3(64, 8, 16), dim3(32, 8), 0, stream>>>(C1, Vt);
  attn_fwd<<<dim3(32, 32), 256, 0, stream>>>(Qb, Kb, Vt, AO);
  gemm256_bt<float><<<240, 512, 131072, stream>>>(AO, Wo, out, 4096, 3840, 4096);
}

// Round 5
// 585.741 us; speedup vs baseline: 1.3694x; 1.0261x over previous
//
#include <hip/hip_runtime.h>
#include <hip/hip_bf16.h>

typedef __hip_bfloat16 BF;
typedef __attribute__((ext_vector_type(8))) short short8;
typedef __attribute__((ext_vector_type(4))) float f32x4;

#define DEV __device__ __forceinline__

// ---------------------------------------------------------------- helpers
DEV void gll16(const BF* g, BF* l) {
  __builtin_amdgcn_global_load_lds(
      (const __attribute__((address_space(1))) void*)g,
      (__attribute__((address_space(3))) void*)l, 16, 0, 0);
}

DEV unsigned short bfbits(float f) {
  BF b = __float2bfloat16(f);
  return *reinterpret_cast<unsigned short*>(&b);
}

// ---------------------------------------------------------------- f32 -> bf16
__global__ void f32_to_bf16_k(const float* __restrict__ in, BF* __restrict__ out, int n4) {
  int i = blockIdx.x * blockDim.x + threadIdx.x;
  if (i >= n4) return;
  const float4 v = ((const float4*)in)[i];
  ((ushort4*)out)[i] = make_ushort4(bfbits(v.x), bfbits(v.y), bfbits(v.z), bfbits(v.w));
}

// f32 -> bf16 with row padding: src rows of 4096 f32 -> dst rows of 4160 bf16
__global__ void f32_to_bf16_pad_k(const float* __restrict__ in, BF* __restrict__ out, int n4) {
  int i = blockIdx.x * blockDim.x + threadIdx.x;
  if (i >= n4) return;
  const float4 v = ((const float4*)in)[i];
  const int r = i >> 10;                 // 1024 float4 per source row (4096 f32)
  const int c = i & 1023;
  ((ushort4*)out)[r * 1040 + c] = make_ushort4(bfbits(v.x), bfbits(v.y), bfbits(v.z), bfbits(v.w));
}

// ---------------------------------------------------------------- 256^2 8-phase GEMM (B^T)
// C[m][n] = sum_k A[m][k]*Bm[n][k].  BM=BN=256, BK=64, 8 waves (2M x 4N),
// per-wave 128x64 out.  LDS: per matrix 2 bufs x [kk(2)][256][32] bf16 = 128 KiB total.
// B fragments read ONCE per kk (p0/p2) and held in registers across both mh phases
// (24 ds_read_b128/wave/K-tile instead of 32 -- LDS-BW was the round-4 bound).
// Deep pipeline: 12 loads in flight, counted vmcnt(8), never 0 in steady state.
#define PHASE(MH, KK, READB, STAGE, TAIL)                                            \
  {                                                                                  \
    short8 af[4];                                                                    \
    const BF* Ap = Ax + (KK)*8192;                                                   \
    _Pragma("unroll") for (int m = 0; m < 4; ++m)                                    \
        af[m] = *(const short8*)&Ap[(wm*128 + (MH)*64 + m*16 + l15) * 32 + rd8];     \
    if (READB) {                                                                     \
      const BF* Bp = Bx + (KK)*8192;                                                 \
      _Pragma("unroll") for (int n = 0; n < 4; ++n)                                  \
          breg[n] = *(const short8*)&Bp[(wn*64 + n*16 + l15) * 32 + rd8];            \
    }                                                                                \
    STAGE                                                                            \
    __builtin_amdgcn_s_barrier();                                                    \
    asm volatile("s_waitcnt lgkmcnt(0)" ::: "memory");                               \
    __builtin_amdgcn_sched_barrier(0);                                               \
    __builtin_amdgcn_s_setprio(1);                                                   \
    _Pragma("unroll") for (int m = 0; m < 4; ++m)                                    \
      _Pragma("unroll") for (int n = 0; n < 4; ++n)                                  \
        acc[(MH)*4 + m][n] =                                                         \
            __builtin_amdgcn_mfma_f32_16x16x32_bf16(af[m], breg[n], acc[(MH)*4+m][n], 0, 0, 0); \
    __builtin_amdgcn_s_setprio(0);                                                   \
    TAIL                                                                             \
    __builtin_amdgcn_s_barrier();                                                    \
  }

template <typename CT>
__global__ __launch_bounds__(512, 2) void gemm256_bt(const BF* __restrict__ A,
                                                     const BF* __restrict__ Bm,
                                                     CT* __restrict__ C,
                                                     const int M, const int N, const int K,
                                                     const int lda, const int ldb) {
  extern __shared__ __align__(16) BF lds[];   // A: [0,32768) elems, B: [32768,65536)
  BF* ldsA = lds;
  BF* ldsB = lds + 32768;
  const int ntl = N >> 8;
  const int cpx = gridDim.x >> 3;              // bijective XCD swizzle (grid % 8 == 0)
  const int swzb = (blockIdx.x & 7) * cpx + (blockIdx.x >> 3);
  const int mt = swzb / ntl, nt = swzb % ntl;
  const int m0 = mt << 8, n0 = nt << 8;
  const int tid = threadIdx.x, lane = tid & 63, w = tid >> 6;
  const int l15 = lane & 15, g = lane >> 4;
  const int wm = w >> 2, wn = w & 3;
  const int rd8 = (g ^ ((l15 >> 1) & 3)) << 3;           // swizzled read slot (elems)
  const int trow = tid >> 2;                             // 0..127
  const int scol = ((lane & 3) ^ ((lane >> 3) & 3)) << 3; // inverse-swizzled src col
  const BF* aS = A + (size_t)(m0 + trow) * lda + scol;
  const BF* bS = Bm + (size_t)(n0 + trow) * ldb + scol;
  const size_t rstpA = (size_t)128 * lda;
  const size_t rstpB = (size_t)128 * ldb;
  BF* dA = ldsA + w * 512;                               // wave-uniform LDS dest base
  BF* dB = ldsB + w * 512;
  const int NT = K >> 6;

  f32x4 acc[8][4];
#pragma unroll
  for (int m = 0; m < 8; ++m)
#pragma unroll
    for (int n = 0; n < 4; ++n) acc[m][n] = (f32x4){0.f, 0.f, 0.f, 0.f};
  short8 breg[4];   // B fragments, persist across mh phases

#define STG2(SRC, RST, DST) { gll16((SRC), (DST)); gll16((SRC) + (RST), (DST) + 4096); }

  // prologue: tile0 (4 halves -> buf0), A_k0(1), B_k0(1) -> buf1  (12 loads in flight)
  STG2(aS, rstpA, dA);
  STG2(bS, rstpB, dB);
  STG2(aS + 32, rstpA, dA + 8192);
  STG2(bS + 32, rstpB, dB + 8192);
  STG2(aS + 64, rstpA, dA + 16384);
  STG2(bS + 64, rstpB, dB + 16384);
  asm volatile("s_waitcnt vmcnt(8)" ::: "memory");   // tile0.kk0 landed
  __builtin_amdgcn_sched_barrier(0);
  __builtin_amdgcn_s_barrier();

  for (int t = 0; t < NT; ++t) {
    const int bX = (t & 1) << 14;                    // 0 or 16384
    const int bY = bX ^ 16384;
    const BF* Ax = ldsA + bX;
    const BF* Bx = ldsB + bX;
    const int kc1 = (t + 1) << 6, kc2 = (t + 2) << 6;
    const bool s1 = (t + 1 < NT), s2 = (t + 2 < NT);
    // p0 (mh0,kk0,readB): stage A_k1(t+1) -> Y.kk1   [dead since t-1 p3]
    PHASE(0, 0, 1, if (s1) STG2(aS + kc1 + 32, rstpA, dA + bY + 8192);, )
    // p1 (mh1,kk0): stage B_k1(t+1) -> Y.kk1;  W2: kk1(t) landed (issued t-1 p0/p1)
    PHASE(1, 0, 0, if (s1) STG2(bS + kc1 + 32, rstpB, dB + bY + 8192);,
          { asm volatile("s_waitcnt vmcnt(8)" ::: "memory");
            __builtin_amdgcn_sched_barrier(0); } )
    // p2 (mh0,kk1,readB): stage A_k0(t+2) -> X.kk0   [dead after p1]
    PHASE(0, 1, 1, if (s2) STG2(aS + kc2, rstpA, dA + bX);, )
    // p3 (mh1,kk1): stage B_k0(t+2) -> X.kk0;  W1: kk0(t+1) landed (issued t-1 p2/p3)
    PHASE(1, 1, 0, if (s2) STG2(bS + kc2, rstpB, dB + bX);,
          if (s2) { asm volatile("s_waitcnt vmcnt(8)" ::: "memory");
                    __builtin_amdgcn_sched_barrier(0); }
          else    { asm volatile("s_waitcnt vmcnt(0)" ::: "memory");
                    __builtin_amdgcn_sched_barrier(0); } )
  }

#pragma unroll
  for (int mi = 0; mi < 8; ++mi) {
    const int gr = m0 + wm * 128 + mi * 16 + g * 4;
#pragma unroll
    for (int n = 0; n < 4; ++n) {
      const int gc = n0 + wn * 64 + n * 16 + l15;
#pragma unroll
      for (int r = 0; r < 4; ++r) {
        const float v = acc[mi][n][r];
        if constexpr (sizeof(CT) == 2)
          C[(size_t)(gr + r) * N + gc] = __float2bfloat16(v);
        else
          C[(size_t)(gr + r) * N + gc] = v;
      }
    }
  }
}

// ---------------------------------------------------------------- RMSNorm + RoPE
__global__ __launch_bounds__(256) void rmsrope(const BF* __restrict__ C1,
                                               BF* __restrict__ Qo, BF* __restrict__ Ko,
                                               const float* __restrict__ cosl,
                                               const float* __restrict__ sinl,
                                               const float* __restrict__ qw,
                                               const float* __restrict__ kw) {
  const int gwid = (blockIdx.x * 256 + threadIdx.x) >> 6;
  const int lane = threadIdx.x & 63;
  const int slot = gwid % 24;
  const int bt = gwid / 24;            // b*2048 + t
  const int b = bt >> 11, t = bt & 2047;
  const BF* src;
  BF* dst;
  const float* wgt;
  if (slot < 16) {
    src = C1 + (size_t)bt * 8192 + slot * 256;
    dst = Qo + ((size_t)(b * 16 + slot) * 2048 + t) * 256;
    wgt = qw;
  } else {
    const int kv = slot - 16;
    src = C1 + (size_t)bt * 8192 + 4096 + kv * 256;
    dst = Ko + ((size_t)(b * 8 + kv) * 2048 + t) * 256;
    wgt = kw;
  }
  const int d2 = lane * 2;
  const ushort2 lo = *(const ushort2*)((const unsigned short*)src + d2);
  const ushort2 hi = *(const ushort2*)((const unsigned short*)src + 128 + d2);
  float x0 = __bfloat162float(*(const BF*)&lo.x);
  float x1 = __bfloat162float(*(const BF*)&lo.y);
  float x2 = __bfloat162float(*(const BF*)&hi.x);
  float x3 = __bfloat162float(*(const BF*)&hi.y);
  float ss = x0 * x0 + x1 * x1 + x2 * x2 + x3 * x3;
#pragma unroll
  for (int mm = 32; mm >= 1; mm >>= 1) ss += __shfl_xor(ss, mm);
  const float nrm = rsqrtf(ss * (1.f / 256.f) + 1e-6f);
  const float2 wlo = *(const float2*)(wgt + d2);
  const float2 whi = *(const float2*)(wgt + 128 + d2);
  x0 *= nrm * wlo.x;
  x1 *= nrm * wlo.y;
  x2 *= nrm * whi.x;
  x3 *= nrm * whi.y;
  const float2 c = *(const float2*)(cosl + t * 128 + d2);
  const float2 s = *(const float2*)(sinl + t * 128 + d2);
  ushort2 olo, ohi;
  olo.x = bfbits(x0 * c.x - x2 * s.x);
  olo.y = bfbits(x1 * c.y - x3 * s.y);
  ohi.x = bfbits(x2 * c.x + x0 * s.x);
  ohi.y = bfbits(x3 * c.y + x1 * s.y);
  *(ushort2*)((unsigned short*)dst + d2) = olo;
  *(ushort2*)((unsigned short*)dst + 128 + d2) = ohi;
}

// ---------------------------------------------------------------- V transpose
__global__ void vtrans(const BF* __restrict__ C1, BF* __restrict__ Vt) {
  __shared__ BF tile[32][33];
  const int bz = blockIdx.z;  // b*8+kv
  const int tt = blockIdx.x;  // t tile
  const int dt = blockIdx.y;  // d tile
  const int x = threadIdx.x, y0 = threadIdx.y;
  const int b = bz >> 3, kv = bz & 7;
#pragma unroll
  for (int yy = y0; yy < 32; yy += 8) {
    const int t = tt * 32 + yy, d = dt * 32 + x;
    tile[yy][x] = C1[((size_t)(b * 2048 + t)) * 8192 + 6144 + kv * 256 + d];
  }
  __syncthreads();
#pragma unroll
  for (int yy = y0; yy < 32; yy += 8) {
    const int d = dt * 32 + yy, t = tt * 32 + x;
    Vt[((size_t)bz * 256 + d) * 2048 + t] = tile[x][yy];
  }
}

// ---------------------------------------------------------------- flash attention
// O written with padded row stride 4160 (de-power-of-2 for GEMM2's staging loads)
__global__ __launch_bounds__(256, 2) void attn_fwd(const BF* __restrict__ Q,
                                                   const BF* __restrict__ K,
                                                   const BF* __restrict__ Vt,
                                                   BF* __restrict__ O) {
  __shared__ __align__(16) BF Ks[64 * 256];
  __shared__ __align__(16) BF Vs[256 * 64];
  __shared__ __align__(16) BF Ps[4][1024];
  const int tid = threadIdx.x;
  const int lane = tid & 63;
  const int w = tid >> 6;
  const int l15 = lane & 15;
  const int g = lane >> 4;
  const int qt = blockIdx.x;
  const int bh = blockIdx.y;
  const int b = bh >> 4, h = bh & 15;
  const int kvh = h >> 1;
  const int q0 = qt << 6;
  const BF* Qb = Q + ((size_t)bh * 2048 + q0) * 256;
  const BF* Kb = K + (size_t)(b * 8 + kvh) * 2048 * 256;
  const BF* Vb = Vt + (size_t)(b * 8 + kvh) * 256 * 2048;

  short8 qf[8];
  {
    const BF* qr = Qb + (w * 16 + l15) * 256 + g * 8;
#pragma unroll
    for (int kk = 0; kk < 8; ++kk) qf[kk] = *(const short8*)(qr + kk * 32);
  }
  f32x4 oacc[16];
#pragma unroll
  for (int i = 0; i < 16; ++i) oacc[i] = (f32x4){0.f, 0.f, 0.f, 0.f};
  float m_r[4] = {-1e30f, -1e30f, -1e30f, -1e30f};
  float l_r[4] = {0.f, 0.f, 0.f, 0.f};

  const int kt_lo = (q0 > 1023) ? ((q0 - 1023) >> 6) : 0;
  for (int kt = kt_lo; kt <= qt; ++kt) {
    const int tk = kt << 6;
#pragma unroll
    for (int i = 0; i < 8; ++i) {
      const int li = w * 8 + i;
      {
        const int row = li * 2 + (lane >> 5);
        const int ch = lane & 31;
        gll16(Kb + (size_t)(tk + row) * 256 + ((ch ^ (row & 7)) << 3), Ks + li * 512);
      }
      {
        const int row = li * 8 + (lane >> 3);
        const int ch = lane & 7;
        gll16(Vb + (size_t)row * 2048 + tk + ((ch ^ (row & 7)) << 3), Vs + li * 512);
      }
    }
    __syncthreads();

    f32x4 sa[4];
#pragma unroll
    for (int i2 = 0; i2 < 4; ++i2) sa[i2] = (f32x4){0.f, 0.f, 0.f, 0.f};
#pragma unroll
    for (int kk = 0; kk < 8; ++kk) {
      const int d = kk * 32 + g * 8;
#pragma unroll
      for (int blk = 0; blk < 4; ++blk) {
        const int row = blk * 16 + l15;
        const short8 kf = *(const short8*)&Ks[row * 256 + (d ^ ((row & 7) << 3))];
        sa[blk] = __builtin_amdgcn_mfma_f32_16x16x32_bf16(qf[kk], kf, sa[blk], 0, 0, 0);
      }
    }

    float al4[4];
#pragma unroll
    for (int r = 0; r < 4; ++r) {
      const int qi = q0 + w * 16 + g * 4 + r;
      float pv[4];
      float tmax = -1e30f;
#pragma unroll
      for (int blk = 0; blk < 4; ++blk) {
        const int ki = tk + blk * 16 + l15;
        float sv = sa[blk][r] * 0.0625f;
        const bool ok = (ki <= qi) && (qi - ki < 1024);
        sv = ok ? sv : -1e30f;
        pv[blk] = sv;
        tmax = fmaxf(tmax, sv);
      }
#pragma unroll
      for (int mm = 1; mm < 16; mm <<= 1) tmax = fmaxf(tmax, __shfl_xor(tmax, mm));
      const float mn = fmaxf(m_r[r], tmax);
      const float alpha = __expf(m_r[r] - mn);
      float tsum = 0.f;
#pragma unroll
      for (int blk = 0; blk < 4; ++blk) {
        const float p = __expf(pv[blk] - mn);
        pv[blk] = p;
        tsum += p;
      }
#pragma unroll
      for (int mm = 1; mm < 16; mm <<= 1) tsum += __shfl_xor(tsum, mm);
      l_r[r] = l_r[r] * alpha + tsum;
      m_r[r] = mn;
      al4[r] = alpha;
      const int prow = g * 4 + r;
#pragma unroll
      for (int blk = 0; blk < 4; ++blk) {
        const int col = blk * 16 + l15;
        Ps[w][prow * 64 + (col ^ ((prow & 7) << 3))] = __float2bfloat16(pv[blk]);
      }
    }
#pragma unroll
    for (int db = 0; db < 16; ++db)
#pragma unroll
      for (int r = 0; r < 4; ++r) oacc[db][r] *= al4[r];

#pragma unroll
    for (int kk2 = 0; kk2 < 2; ++kk2) {
      const int k8 = kk2 * 32 + g * 8;
      const short8 pf = *(const short8*)&Ps[w][l15 * 64 + (k8 ^ ((l15 & 7) << 3))];
#pragma unroll
      for (int db = 0; db < 16; ++db) {
        const int vrow = db * 16 + l15;
        const short8 vf = *(const short8*)&Vs[vrow * 64 + (k8 ^ ((vrow & 7) << 3))];
        oacc[db] = __builtin_amdgcn_mfma_f32_16x16x32_bf16(pf, vf, oacc[db], 0, 0, 0);
      }
    }
    __syncthreads();
  }

#pragma unroll
  for (int r = 0; r < 4; ++r) l_r[r] = 1.f / l_r[r];
  const size_t orow0 = (size_t)(b * 2048 + q0 + w * 16 + g * 4);
#pragma unroll
  for (int r = 0; r < 4; ++r) {
    BF* op = O + (orow0 + r) * 4160 + h * 256 + l15;
#pragma unroll
    for (int db = 0; db < 16; ++db) op[db * 16] = __float2bfloat16(oacc[db][r] * l_r[r]);
  }
}

// ---------------------------------------------------------------- launcher
// ws layout (bytes), lifetimes verified disjoint per step:
//   [0        , 62914560 )  Wqkv bf16          -> after GEMM1: Qb (33554432) + Kb@33554432 (16777216)
//   [62914560 , 94371840 )  Xbf bf16 (31457280) -> after GEMM1: Vt (16777216)
//   [94371840 , 161480704)  C1 bf16 (67108864)  -> after vtrans: AO padded (34078720) + Wo padded @128450560 (31948800)
extern "C" void kernel_launch(void* const* d_in, const int* in_sizes, int n_in,
                              void* d_out, int out_size, void* d_ws, size_t ws_size,
                              hipStream_t stream) {
  (void)in_sizes; (void)n_in; (void)out_size;
  const float* x    = (const float*)d_in[0];
  const float* cosl = (const float*)d_in[3];   // reference uses LOCAL tables for q and k
  const float* sinl = (const float*)d_in[4];
  const float* wq   = (const float*)d_in[6];
  const float* wk   = (const float*)d_in[7];
  const float* wv   = (const float*)d_in[8];
  const float* wo   = (const float*)d_in[9];
  const float* qw   = (const float*)d_in[10];
  const float* kw   = (const float*)d_in[11];
  float* out = (float*)d_out;
  char* ws = (char*)d_ws;
  if (ws_size < 161480704ull) return;

  BF* Wqkv = (BF*)(ws + 0);
  BF* Xbf  = (BF*)(ws + 62914560);
  BF* C1   = (BF*)(ws + 94371840);
  BF* Qb   = (BF*)(ws + 0);            // alias (Wqkv dead after GEMM1)
  BF* Kb   = (BF*)(ws + 33554432);
  BF* Vt   = (BF*)(ws + 62914560);     // alias (Xbf dead after GEMM1)
  BF* AO   = (BF*)(ws + 94371840);     // alias (C1 dead after vtrans), rows padded to 4160
  BF* Wo   = (BF*)(ws + 128450560);    // rows padded to 4160

  hipFuncSetAttribute(reinterpret_cast<const void*>(gemm256_bt<BF>),
                      hipFuncAttributeMaxDynamicSharedMemorySize, 131072);
  hipFuncSetAttribute(reinterpret_cast<const void*>(gemm256_bt<float>),
                      hipFuncAttributeMaxDynamicSharedMemorySize, 131072);

  auto cvt = [&](const float* src, BF* dst, int n) {
    const int n4 = n >> 2;
    f32_to_bf16_k<<<(n4 + 255) / 256, 256, 0, stream>>>(src, dst, n4);
  };
  cvt(x,  Xbf, 4096 * 3840);
  cvt(wq, Wqkv, 4096 * 3840);
  cvt(wk, Wqkv + 4096 * 3840, 2048 * 3840);
  cvt(wv, Wqkv + 6144 * 3840, 2048 * 3840);

  gemm256_bt<BF><<<512, 512, 131072, stream>>>(Xbf, Wqkv, C1, 4096, 8192, 3840, 3840, 3840);
  rmsrope<<<24576, 256, 0, stream>>>(C1, Qb, Kb, cosl, sinl, qw, kw);
  vtrans<<<dim3(64, 8, 16), dim3(32, 8), 0, stream>>>(C1, Vt);
  // Wo conversion (padded rows): C1 region dead after vtrans; Wo region disjoint from AO
  {
    const int n4 = (3840 * 4096) >> 2;
    f32_to_bf16_pad_k<<<(n4 + 255) / 256, 256, 0, stream>>>(wo, Wo, n4);
  }
  attn_fwd<<<dim3(32, 32), 256, 0, stream>>>(Qb, Kb, Vt, AO);
  gemm256_bt<float><<<240, 512, 131072, stream>>>(AO, Wo, out, 4096, 3840, 4096, 4160, 4160);
}

// Round 7
// 577.396 us; speedup vs baseline: 1.3892x; 1.0145x over previous
//
#include <hip/hip_runtime.h>
#include <hip/hip_bf16.h>

typedef __hip_bfloat16 BF;
typedef __attribute__((ext_vector_type(8))) short short8;
typedef __attribute__((ext_vector_type(4))) float f32x4;

#define DEV __device__ __forceinline__

// ---------------------------------------------------------------- helpers
DEV void gll16(const BF* g, BF* l) {
  __builtin_amdgcn_global_load_lds(
      (const __attribute__((address_space(1))) void*)g,
      (__attribute__((address_space(3))) void*)l, 16, 0, 0);
}

DEV unsigned short bfbits(float f) {
  BF b = __float2bfloat16(f);
  return *reinterpret_cast<unsigned short*>(&b);
}

// ---------------------------------------------------------------- f32 -> bf16
__global__ void f32_to_bf16_k(const float* __restrict__ in, BF* __restrict__ out, int n4) {
  int i = blockIdx.x * blockDim.x + threadIdx.x;
  if (i >= n4) return;
  const float4 v = ((const float4*)in)[i];
  ((ushort4*)out)[i] = make_ushort4(bfbits(v.x), bfbits(v.y), bfbits(v.z), bfbits(v.w));
}

// f32 -> bf16 with row padding: src rows of 4096 f32 -> dst rows of 4160 bf16
__global__ void f32_to_bf16_pad_k(const float* __restrict__ in, BF* __restrict__ out, int n4) {
  int i = blockIdx.x * blockDim.x + threadIdx.x;
  if (i >= n4) return;
  const float4 v = ((const float4*)in)[i];
  const int r = i >> 10;                 // 1024 float4 per source row (4096 f32)
  const int c = i & 1023;
  ((ushort4*)out)[r * 1040 + c] = make_ushort4(bfbits(v.x), bfbits(v.y), bfbits(v.z), bfbits(v.w));
}

// ---------------------------------------------------------------- 256^2 8-phase GEMM (B^T)
// C[m][n] = sum_k A[m][k]*Bm[n][k].  BM=BN=256, BK=64, 8 waves (2M x 4N),
// per-wave 128x64 out.  LDS: per matrix 2 bufs x [kk(2)][256][32] bf16 = 128 KiB total.
// B fragments read once per kk (p0/p2), held in registers across both mh phases.
// Deep pipeline: 12 loads in flight, counted vmcnt(8), never 0 in steady state.
#define PHASE(MH, KK, READB, STAGE, TAIL)                                            \
  {                                                                                  \
    short8 af[4];                                                                    \
    const BF* Ap = Ax + (KK)*8192;                                                   \
    _Pragma("unroll") for (int m = 0; m < 4; ++m)                                    \
        af[m] = *(const short8*)&Ap[(wm*128 + (MH)*64 + m*16 + l15) * 32 + rd8];     \
    if (READB) {                                                                     \
      const BF* Bp = Bx + (KK)*8192;                                                 \
      _Pragma("unroll") for (int n = 0; n < 4; ++n)                                  \
          breg[n] = *(const short8*)&Bp[(wn*64 + n*16 + l15) * 32 + rd8];            \
    }                                                                                \
    STAGE                                                                            \
    __builtin_amdgcn_s_barrier();                                                    \
    asm volatile("s_waitcnt lgkmcnt(0)" ::: "memory");                               \
    __builtin_amdgcn_sched_barrier(0);                                               \
    __builtin_amdgcn_s_setprio(1);                                                   \
    _Pragma("unroll") for (int m = 0; m < 4; ++m)                                    \
      _Pragma("unroll") for (int n = 0; n < 4; ++n)                                  \
        acc[(MH)*4 + m][n] =                                                         \
            __builtin_amdgcn_mfma_f32_16x16x32_bf16(af[m], breg[n], acc[(MH)*4+m][n], 0, 0, 0); \
    __builtin_amdgcn_s_setprio(0);                                                   \
    TAIL                                                                             \
    __builtin_amdgcn_s_barrier();                                                    \
  }

template <typename CT>
DEV void gemm256_body(const BF* __restrict__ A, const BF* __restrict__ Bm,
                      CT* __restrict__ C, const int M, const int N, const int K,
                      const int lda, const int ldb) {
  extern __shared__ __align__(16) BF lds[];   // A: [0,32768) elems, B: [32768,65536)
  BF* ldsA = lds;
  BF* ldsB = lds + 32768;
  const int ntl = N >> 8;
  const int mtl = M >> 8;
  int mt, nt;
  if (mtl == 16 && ntl == 32) {
    // 2-D chunked XCD raster: each XCD owns an 8mt x 8nt region (32 MB working
    // set instead of 90 MB) -> L2-miss fetch drops.
    const int x = blockIdx.x & 7;        // XCD
    const int c = blockIdx.x >> 3;       // 0..63 within region
    mt = ((x >> 2) << 3) + (c >> 3);
    nt = ((x & 3) << 3) + (c & 7);
  } else {
    // bijective 1-D XCD swizzle (grid % 8 == 0)
    const int cpx = gridDim.x >> 3;
    const int swzb = (blockIdx.x & 7) * cpx + (blockIdx.x >> 3);
    mt = swzb / ntl;
    nt = swzb % ntl;
  }
  const int m0 = mt << 8, n0 = nt << 8;
  const int tid = threadIdx.x, lane = tid & 63, w = tid >> 6;
  const int l15 = lane & 15, g = lane >> 4;
  const int wm = w >> 2, wn = w & 3;
  const int rd8 = (g ^ ((l15 >> 1) & 3)) << 3;           // swizzled read slot (elems)
  const int trow = tid >> 2;                             // 0..127
  const int scol = ((lane & 3) ^ ((lane >> 3) & 3)) << 3; // inverse-swizzled src col
  const BF* aS = A + (size_t)(m0 + trow) * lda + scol;
  const BF* bS = Bm + (size_t)(n0 + trow) * ldb + scol;
  const size_t rstpA = (size_t)128 * lda;
  const size_t rstpB = (size_t)128 * ldb;
  BF* dA = ldsA + w * 512;                               // wave-uniform LDS dest base
  BF* dB = ldsB + w * 512;
  const int NT = K >> 6;

  f32x4 acc[8][4];
#pragma unroll
  for (int m = 0; m < 8; ++m)
#pragma unroll
    for (int n = 0; n < 4; ++n) acc[m][n] = (f32x4){0.f, 0.f, 0.f, 0.f};
  short8 breg[4];   // B fragments, persist across mh phases

#define STG2(SRC, RST, DST) { gll16((SRC), (DST)); gll16((SRC) + (RST), (DST) + 4096); }

  // prologue: tile0 (4 halves -> buf0), A_k0(1), B_k0(1) -> buf1  (12 loads in flight)
  STG2(aS, rstpA, dA);
  STG2(bS, rstpB, dB);
  STG2(aS + 32, rstpA, dA + 8192);
  STG2(bS + 32, rstpB, dB + 8192);
  STG2(aS + 64, rstpA, dA + 16384);
  STG2(bS + 64, rstpB, dB + 16384);
  asm volatile("s_waitcnt vmcnt(8)" ::: "memory");   // tile0.kk0 landed
  __builtin_amdgcn_sched_barrier(0);
  __builtin_amdgcn_s_barrier();

  for (int t = 0; t < NT; ++t) {
    const int bX = (t & 1) << 14;                    // 0 or 16384
    const int bY = bX ^ 16384;
    const BF* Ax = ldsA + bX;
    const BF* Bx = ldsB + bX;
    const int kc1 = (t + 1) << 6, kc2 = (t + 2) << 6;
    const bool s1 = (t + 1 < NT), s2 = (t + 2 < NT);
    // p0 (mh0,kk0,readB): stage A_k1(t+1) -> Y.kk1   [dead since t-1 p3]
    PHASE(0, 0, 1, if (s1) STG2(aS + kc1 + 32, rstpA, dA + bY + 8192);, )
    // p1 (mh1,kk0): stage B_k1(t+1) -> Y.kk1;  W2: kk1(t) landed (issued t-1 p0/p1)
    PHASE(1, 0, 0, if (s1) STG2(bS + kc1 + 32, rstpB, dB + bY + 8192);,
          { asm volatile("s_waitcnt vmcnt(8)" ::: "memory");
            __builtin_amdgcn_sched_barrier(0); } )
    // p2 (mh0,kk1,readB): stage A_k0(t+2) -> X.kk0   [dead after p1]
    PHASE(0, 1, 1, if (s2) STG2(aS + kc2, rstpA, dA + bX);, )
    // p3 (mh1,kk1): stage B_k0(t+2) -> X.kk0;  W1: kk0(t+1) landed (issued t-1 p2/p3)
    PHASE(1, 1, 0, if (s2) STG2(bS + kc2, rstpB, dB + bX);,
          if (s2) { asm volatile("s_waitcnt vmcnt(8)" ::: "memory");
                    __builtin_amdgcn_sched_barrier(0); }
          else    { asm volatile("s_waitcnt vmcnt(0)" ::: "memory");
                    __builtin_amdgcn_sched_barrier(0); } )
  }

#pragma unroll
  for (int mi = 0; mi < 8; ++mi) {
    const int gr = m0 + wm * 128 + mi * 16 + g * 4;
#pragma unroll
    for (int n = 0; n < 4; ++n) {
      const int gc = n0 + wn * 64 + n * 16 + l15;
#pragma unroll
      for (int r = 0; r < 4; ++r) {
        const float v = acc[mi][n][r];
        if constexpr (sizeof(CT) == 2)
          C[(size_t)(gr + r) * N + gc] = __float2bfloat16(v);
        else
          C[(size_t)(gr + r) * N + gc] = v;
      }
    }
  }
}

// distinct names so rocprof separates the two GEMMs
__global__ __launch_bounds__(512, 2) void gemm_qkv(const BF* __restrict__ A,
                                                   const BF* __restrict__ Bm,
                                                   BF* __restrict__ C,
                                                   int M, int N, int K, int lda, int ldb) {
  gemm256_body<BF>(A, Bm, C, M, N, K, lda, ldb);
}
__global__ __launch_bounds__(512, 2) void gemm_out(const BF* __restrict__ A,
                                                   const BF* __restrict__ Bm,
                                                   float* __restrict__ C,
                                                   int M, int N, int K, int lda, int ldb) {
  gemm256_body<float>(A, Bm, C, M, N, K, lda, ldb);
}

// ---------------------------------------------------------------- RMSNorm + RoPE
__global__ __launch_bounds__(256) void rmsrope(const BF* __restrict__ C1,
                                               BF* __restrict__ Qo, BF* __restrict__ Ko,
                                               const float* __restrict__ cosl,
                                               const float* __restrict__ sinl,
                                               const float* __restrict__ qw,
                                               const float* __restrict__ kw) {
  const int gwid = (blockIdx.x * 256 + threadIdx.x) >> 6;
  const int lane = threadIdx.x & 63;
  const int slot = gwid % 24;
  const int bt = gwid / 24;            // b*2048 + t
  const int b = bt >> 11, t = bt & 2047;
  const BF* src;
  BF* dst;
  const float* wgt;
  if (slot < 16) {
    src = C1 + (size_t)bt * 8192 + slot * 256;
    dst = Qo + ((size_t)(b * 16 + slot) * 2048 + t) * 256;
    wgt = qw;
  } else {
    const int kv = slot - 16;
    src = C1 + (size_t)bt * 8192 + 4096 + kv * 256;
    dst = Ko + ((size_t)(b * 8 + kv) * 2048 + t) * 256;
    wgt = kw;
  }
  const int d2 = lane * 2;
  const ushort2 lo = *(const ushort2*)((const unsigned short*)src + d2);
  const ushort2 hi = *(const ushort2*)((const unsigned short*)src + 128 + d2);
  float x0 = __bfloat162float(*(const BF*)&lo.x);
  float x1 = __bfloat162float(*(const BF*)&lo.y);
  float x2 = __bfloat162float(*(const BF*)&hi.x);
  float x3 = __bfloat162float(*(const BF*)&hi.y);
  float ss = x0 * x0 + x1 * x1 + x2 * x2 + x3 * x3;
#pragma unroll
  for (int mm = 32; mm >= 1; mm >>= 1) ss += __shfl_xor(ss, mm);
  const float nrm = rsqrtf(ss * (1.f / 256.f) + 1e-6f);
  const float2 wlo = *(const float2*)(wgt + d2);
  const float2 whi = *(const float2*)(wgt + 128 + d2);
  x0 *= nrm * wlo.x;
  x1 *= nrm * wlo.y;
  x2 *= nrm * whi.x;
  x3 *= nrm * whi.y;
  const float2 c = *(const float2*)(cosl + t * 128 + d2);
  const float2 s = *(const float2*)(sinl + t * 128 + d2);
  ushort2 olo, ohi;
  olo.x = bfbits(x0 * c.x - x2 * s.x);
  olo.y = bfbits(x1 * c.y - x3 * s.y);
  ohi.x = bfbits(x2 * c.x + x0 * s.x);
  ohi.y = bfbits(x3 * c.y + x1 * s.y);
  *(ushort2*)((unsigned short*)dst + d2) = olo;
  *(ushort2*)((unsigned short*)dst + 128 + d2) = ohi;
}

// ---------------------------------------------------------------- V transpose
__global__ void vtrans(const BF* __restrict__ C1, BF* __restrict__ Vt) {
  __shared__ BF tile[32][33];
  const int bz = blockIdx.z;  // b*8+kv
  const int tt = blockIdx.x;  // t tile
  const int dt = blockIdx.y;  // d tile
  const int x = threadIdx.x, y0 = threadIdx.y;
  const int b = bz >> 3, kv = bz & 7;
#pragma unroll
  for (int yy = y0; yy < 32; yy += 8) {
    const int t = tt * 32 + yy, d = dt * 32 + x;
    tile[yy][x] = C1[((size_t)(b * 2048 + t)) * 8192 + 6144 + kv * 256 + d];
  }
  __syncthreads();
#pragma unroll
  for (int yy = y0; yy < 32; yy += 8) {
    const int d = dt * 32 + yy, t = tt * 32 + x;
    Vt[((size_t)bz * 256 + d) * 2048 + t] = tile[x][yy];
  }
}

// ---------------------------------------------------------------- flash attention
// Round-5-exact body (T13 rescale-skip reverted).  O row stride 4160.
__global__ __launch_bounds__(256, 2) void attn_fwd(const BF* __restrict__ Q,
                                                   const BF* __restrict__ K,
                                                   const BF* __restrict__ Vt,
                                                   BF* __restrict__ O) {
  __shared__ __align__(16) BF Ks[64 * 256];
  __shared__ __align__(16) BF Vs[256 * 64];
  __shared__ __align__(16) BF Ps[4][1024];
  const int tid = threadIdx.x;
  const int lane = tid & 63;
  const int w = tid >> 6;
  const int l15 = lane & 15;
  const int g = lane >> 4;
  const int qt = blockIdx.x;
  const int bh = blockIdx.y;
  const int b = bh >> 4, h = bh & 15;
  const int kvh = h >> 1;
  const int q0 = qt << 6;
  const BF* Qb = Q + ((size_t)bh * 2048 + q0) * 256;
  const BF* Kb = K + (size_t)(b * 8 + kvh) * 2048 * 256;
  const BF* Vb = Vt + (size_t)(b * 8 + kvh) * 256 * 2048;

  short8 qf[8];
  {
    const BF* qr = Qb + (w * 16 + l15) * 256 + g * 8;
#pragma unroll
    for (int kk = 0; kk < 8; ++kk) qf[kk] = *(const short8*)(qr + kk * 32);
  }
  f32x4 oacc[16];
#pragma unroll
  for (int i = 0; i < 16; ++i) oacc[i] = (f32x4){0.f, 0.f, 0.f, 0.f};
  float m_r[4] = {-1e30f, -1e30f, -1e30f, -1e30f};
  float l_r[4] = {0.f, 0.f, 0.f, 0.f};

  const int kt_lo = (q0 > 1023) ? ((q0 - 1023) >> 6) : 0;
  for (int kt = kt_lo; kt <= qt; ++kt) {
    const int tk = kt << 6;
#pragma unroll
    for (int i = 0; i < 8; ++i) {
      const int li = w * 8 + i;
      {
        const int row = li * 2 + (lane >> 5);
        const int ch = lane & 31;
        gll16(Kb + (size_t)(tk + row) * 256 + ((ch ^ (row & 7)) << 3), Ks + li * 512);
      }
      {
        const int row = li * 8 + (lane >> 3);
        const int ch = lane & 7;
        gll16(Vb + (size_t)row * 2048 + tk + ((ch ^ (row & 7)) << 3), Vs + li * 512);
      }
    }
    __syncthreads();

    f32x4 sa[4];
#pragma unroll
    for (int i2 = 0; i2 < 4; ++i2) sa[i2] = (f32x4){0.f, 0.f, 0.f, 0.f};
#pragma unroll
    for (int kk = 0; kk < 8; ++kk) {
      const int d = kk * 32 + g * 8;
#pragma unroll
      for (int blk = 0; blk < 4; ++blk) {
        const int row = blk * 16 + l15;
        const short8 kf = *(const short8*)&Ks[row * 256 + (d ^ ((row & 7) << 3))];
        sa[blk] = __builtin_amdgcn_mfma_f32_16x16x32_bf16(qf[kk], kf, sa[blk], 0, 0, 0);
      }
    }

    float al4[4];
#pragma unroll
    for (int r = 0; r < 4; ++r) {
      const int qi = q0 + w * 16 + g * 4 + r;
      float pv[4];
      float tmax = -1e30f;
#pragma unroll
      for (int blk = 0; blk < 4; ++blk) {
        const int ki = tk + blk * 16 + l15;
        float sv = sa[blk][r] * 0.0625f;
        const bool ok = (ki <= qi) && (qi - ki < 1024);
        sv = ok ? sv : -1e30f;
        pv[blk] = sv;
        tmax = fmaxf(tmax, sv);
      }
#pragma unroll
      for (int mm = 1; mm < 16; mm <<= 1) tmax = fmaxf(tmax, __shfl_xor(tmax, mm));
      const float mn = fmaxf(m_r[r], tmax);
      const float alpha = __expf(m_r[r] - mn);
      float tsum = 0.f;
#pragma unroll
      for (int blk = 0; blk < 4; ++blk) {
        const float p = __expf(pv[blk] - mn);
        pv[blk] = p;
        tsum += p;
      }
#pragma unroll
      for (int mm = 1; mm < 16; mm <<= 1) tsum += __shfl_xor(tsum, mm);
      l_r[r] = l_r[r] * alpha + tsum;
      m_r[r] = mn;
      al4[r] = alpha;
      const int prow = g * 4 + r;
#pragma unroll
      for (int blk = 0; blk < 4; ++blk) {
        const int col = blk * 16 + l15;
        Ps[w][prow * 64 + (col ^ ((prow & 7) << 3))] = __float2bfloat16(pv[blk]);
      }
    }
#pragma unroll
    for (int db = 0; db < 16; ++db)
#pragma unroll
      for (int r = 0; r < 4; ++r) oacc[db][r] *= al4[r];

#pragma unroll
    for (int kk2 = 0; kk2 < 2; ++kk2) {
      const int k8 = kk2 * 32 + g * 8;
      const short8 pf = *(const short8*)&Ps[w][l15 * 64 + (k8 ^ ((l15 & 7) << 3))];
#pragma unroll
      for (int db = 0; db < 16; ++db) {
        const int vrow = db * 16 + l15;
        const short8 vf = *(const short8*)&Vs[vrow * 64 + (k8 ^ ((vrow & 7) << 3))];
        oacc[db] = __builtin_amdgcn_mfma_f32_16x16x32_bf16(pf, vf, oacc[db], 0, 0, 0);
      }
    }
    __syncthreads();
  }

#pragma unroll
  for (int r = 0; r < 4; ++r) l_r[r] = 1.f / l_r[r];
  const size_t orow0 = (size_t)(b * 2048 + q0 + w * 16 + g * 4);
#pragma unroll
  for (int r = 0; r < 4; ++r) {
    BF* op = O + (orow0 + r) * 4160 + h * 256 + l15;
#pragma unroll
    for (int db = 0; db < 16; ++db) op[db * 16] = __float2bfloat16(oacc[db][r] * l_r[r]);
  }
}

// ---------------------------------------------------------------- launcher
// ws layout (bytes), lifetimes verified disjoint per step:
//   [0        , 62914560 )  Wqkv bf16          -> after GEMM1: Qb (33554432) + Kb@33554432 (16777216)
//   [62914560 , 94371840 )  Xbf bf16 (31457280) -> after GEMM1: Vt (16777216)
//   [94371840 , 161480704)  C1 bf16 (67108864)  -> after vtrans: AO padded (34078720) + Wo padded @128450560 (31948800)
extern "C" void kernel_launch(void* const* d_in, const int* in_sizes, int n_in,
                              void* d_out, int out_size, void* d_ws, size_t ws_size,
                              hipStream_t stream) {
  (void)in_sizes; (void)n_in; (void)out_size;
  const float* x    = (const float*)d_in[0];
  const float* cosl = (const float*)d_in[3];   // reference uses LOCAL tables for q and k
  const float* sinl = (const float*)d_in[4];
  const float* wq   = (const float*)d_in[6];
  const float* wk   = (const float*)d_in[7];
  const float* wv   = (const float*)d_in[8];
  const float* wo   = (const float*)d_in[9];
  const float* qw   = (const float*)d_in[10];
  const float* kw   = (const float*)d_in[11];
  float* out = (float*)d_out;
  char* ws = (char*)d_ws;
  if (ws_size < 161480704ull) return;

  BF* Wqkv = (BF*)(ws + 0);
  BF* Xbf  = (BF*)(ws + 62914560);
  BF* C1   = (BF*)(ws + 94371840);
  BF* Qb   = (BF*)(ws + 0);            // alias (Wqkv dead after GEMM1)
  BF* Kb   = (BF*)(ws + 33554432);
  BF* Vt   = (BF*)(ws + 62914560);     // alias (Xbf dead after GEMM1)
  BF* AO   = (BF*)(ws + 94371840);     // alias (C1 dead after vtrans), rows padded to 4160
  BF* Wo   = (BF*)(ws + 128450560);    // rows padded to 4160

  hipFuncSetAttribute(reinterpret_cast<const void*>(gemm_qkv),
                      hipFuncAttributeMaxDynamicSharedMemorySize, 131072);
  hipFuncSetAttribute(reinterpret_cast<const void*>(gemm_out),
                      hipFuncAttributeMaxDynamicSharedMemorySize, 131072);

  auto cvt = [&](const float* src, BF* dst, int n) {
    const int n4 = n >> 2;
    f32_to_bf16_k<<<(n4 + 255) / 256, 256, 0, stream>>>(src, dst, n4);
  };
  cvt(x,  Xbf, 4096 * 3840);
  cvt(wq, Wqkv, 4096 * 3840);
  cvt(wk, Wqkv + 4096 * 3840, 2048 * 3840);
  cvt(wv, Wqkv + 6144 * 3840, 2048 * 3840);

  gemm_qkv<<<512, 512, 131072, stream>>>(Xbf, Wqkv, C1, 4096, 8192, 3840, 3840, 3840);
  rmsrope<<<24576, 256, 0, stream>>>(C1, Qb, Kb, cosl, sinl, qw, kw);
  vtrans<<<dim3(64, 8, 16), dim3(32, 8), 0, stream>>>(C1, Vt);
  {
    const int n4 = (3840 * 4096) >> 2;
    f32_to_bf16_pad_k<<<(n4 + 255) / 256, 256, 0, stream>>>(wo, Wo, n4);
  }
  attn_fwd<<<dim3(32, 32), 256, 0, stream>>>(Qb, Kb, Vt, AO);
  gemm_out<<<240, 512, 131072, stream>>>(AO, Wo, out, 4096, 3840, 4096, 4160, 4160);
}